// Round 5
// baseline (2922.972 us; speedup 1.0000x reference)
//
#include <hip/hip_runtime.h>
#include <math.h>

#define N_NODES 8192
#define N_EDGES 262144
#define INV_SQRT3 0.5773502691896258f

__device__ __forceinline__ float sspf(float x){
    // softplus(x) - ln(2), numerically stable
    float sp = (x > 20.0f) ? x : log1pf(expf(x));
    return sp - 0.6931471805599453f;
}

__device__ __forceinline__ float bcast_lane(float v, int u){
    return __uint_as_float(__builtin_amdgcn_readlane(__float_as_uint(v), u));
}

// ---------------------------------------------------------------------------
// Kernel A: per-node: out = sc (self-connection);
// qd = Wd^T q with all d-stage scales folded in:
//   qd0[v]    = (1/sqrt(2048))       * sum_u q0[u]    * Wd0[u][v]
//   qd1[v][c] = (1/sqrt(2048)/sqrt3)* sum_u q1[u][c] * Wd1[u][v]
// qd layout per node (128): qd0[0..31], qd1 at 32+v*3+c  (matches k layout)
// ---------------------------------------------------------------------------
__global__ __launch_bounds__(128) void node_kernel(
    const float* __restrict__ feats, const float* __restrict__ attrs,
    const float* __restrict__ Wq0, const float* __restrict__ Wq1,
    const float* __restrict__ Wd0, const float* __restrict__ Wd1,
    const float* __restrict__ Ws0, const float* __restrict__ Ws1,
    float* __restrict__ qdbuf, float* __restrict__ out)
{
    int n = blockIdx.x; int t = threadIdx.x;
    __shared__ float sf[128];
    __shared__ float sa[16];
    __shared__ float sq[128];
    sf[t] = feats[n*128 + t];
    if (t < 16) sa[t] = attrs[n*16 + t];
    __syncthreads();
    const float inv_sqrt32 = 0.17677669529663687f;   // 1/sqrt(32)
    const float sc_scale   = 0.04419417382415922f;   // 1/sqrt(32*16)
    const float d_scale    = 0.022097086912079608f;  // 1/sqrt(2*32*32)
    float qv, scv;
    if (t < 32){
        int v = t;
        float acc = 0.f;
        for (int u = 0; u < 32; ++u) acc += sf[u] * Wq0[u*32 + v];
        qv = acc * inv_sqrt32;
        acc = 0.f;
        for (int u = 0; u < 32; ++u){
            float su = sf[u];
            for (int a = 0; a < 16; ++a)
                acc += su * sa[a] * Ws0[(u*16 + a)*32 + v];
        }
        scv = acc * sc_scale;
    } else {
        int k = t - 32; int v = k/3; int c = k - v*3;
        float acc = 0.f;
        for (int u = 0; u < 32; ++u) acc += sf[32 + u*3 + c] * Wq1[u*32 + v];
        qv = acc * inv_sqrt32;
        acc = 0.f;
        for (int u = 0; u < 32; ++u){
            float su = sf[32 + u*3 + c];
            for (int a = 0; a < 16; ++a)
                acc += su * sa[a] * Ws1[(u*16 + a)*32 + v];
        }
        scv = acc * sc_scale;
    }
    sq[t] = qv;
    out[n*128 + t] = scv;
    __syncthreads();

    float qd;
    if (t < 32){
        int v = t;
        float acc = 0.f;
        for (int u = 0; u < 32; ++u) acc += sq[u] * Wd0[u*32 + v];
        qd = acc * d_scale;
    } else {
        int k = t - 32; int v = k/3; int c = k - v*3;
        float acc = 0.f;
        for (int u = 0; u < 32; ++u) acc += sq[32 + u*3 + c] * Wd1[u*32 + v];
        qd = acc * d_scale * INV_SQRT3;
    }
    qdbuf[n*128 + t] = qd;
}

// ---------------------------------------------------------------------------
// Edge pass kernels: 4 edges per wave-iteration, 64 edges per wave.
// LDS (12544 dwords = 50176 B -> 3 blocks/CU):
//   W2 permuted @ 0 (8192): [u][lane] -> float2{W2[u][c1(lane)],W2[u][c2]}*0.125
//   scratch @ 8192: 4 waves x 4 edges x 272 dwords; km planes at +0/68/136/204
//     (offsets = {0,4,8,12} mod 32 -> conflict-free 4-group b128 lin reads)
// h kept in registers, broadcast via v_readlane (no per-lane weight arrays ->
// no scratch spill, VGPR ~<130). No per-iteration barriers (per-wave scratch).
// ---------------------------------------------------------------------------
__global__ __launch_bounds__(256, 3) void edge_pass1(
    const float* __restrict__ feats, const float* __restrict__ emb,
    const float* __restrict__ eattr, const int* __restrict__ eidx,
    const float* __restrict__ Wk1, const float* __restrict__ Wk2,
    const float* __restrict__ Wlk0, const float* __restrict__ Wlk1,
    const float* __restrict__ qdbuf,
    float* __restrict__ expv_buf, float* __restrict__ zbuf)
{
    __shared__ float lds[12544];
    const int t    = threadIdx.x;
    const int lane = t & 63;
    const bool low = lane < 32;
    const int c1 = low ? lane : lane + 32;   // owned GEMM2 output cols
    const int c2 = c1 + 32;

    {   // permuted + prescaled W2 preload (all 4 waves cooperate)
        const int wvz = t >> 6;
        for (int u = wvz; u < 64; u += 4){
            lds[(u*64+lane)*2+0] = Wk2[u*128 + c1] * 0.125f;
            lds[(u*64+lane)*2+1] = Wk2[u*128 + c2] * 0.125f;
        }
    }
    float wk1r[16];
    #pragma unroll
    for (int a = 0; a < 16; ++a) wk1r[a] = Wk1[a*64 + lane] * 0.25f;
    __syncthreads();   // the only barrier

    const int wv = __builtin_amdgcn_readfirstlane(t >> 6);
    const int sb = 8192 + wv*1088;           // wave scratch: 4 edges x 272

    // lin-stage lane constants: lane owns outputs o0,o1
    const int p  = lane >> 4;                // 0..3
    const int v0 = (2*lane) & 31;
    const float* __restrict__ wlin = ((p==0)? Wlk0 : Wlk1) + v0;
    const int poff = (p==0)? 0 : (68 + (p-1)*68);   // 0,68,136,204
    const int o0 = (p==0)? v0     : 32 + v0*3     + (p-1);
    const int o1 = (p==0)? v0 + 1 : 32 + (v0+1)*3 + (p-1);

    const int xsi = low ? lane : (32 + 3*(lane-32));
    const int ebase = (blockIdx.x*4 + wv) * 64;

    for (int it = 0; it < 16; ++it){
        const int e0 = __builtin_amdgcn_readfirstlane(ebase + 4*it);
        int src[4], dst[4];
        #pragma unroll
        for (int j = 0; j < 4; ++j){
            src[j] = eidx[e0+j]; dst[j] = eidx[N_EDGES+e0+j];
        }

        // ---- GEMM1: h[j] = ssp(emb@Wk1/4) per edge, in registers ----
        float h[4];
        #pragma unroll
        for (int j = 0; j < 4; ++j){
            const float4* em = (const float4*)(emb + (size_t)(e0+j)*16);
            float acc = 0.f;
            #pragma unroll
            for (int a4 = 0; a4 < 4; ++a4){
                float4 v = em[a4];
                acc += v.x*wk1r[a4*4+0] + v.y*wk1r[a4*4+1]
                     + v.z*wk1r[a4*4+2] + v.w*wk1r[a4*4+3];
            }
            h[j] = sspf(acc);
        }

        // ---- GEMM2: w = h@Wk2/8; weights b64 from LDS (shared over 4 edges),
        //      h broadcast via readlane; accumulate in regs ----
        float wa[4] = {0,0,0,0}, wb[4] = {0,0,0,0};
        #pragma unroll
        for (int u = 0; u < 64; ++u){
            float2 w2 = *(const float2*)&lds[(u*64+lane)*2];
            #pragma unroll
            for (int j = 0; j < 4; ++j){
                float s = bcast_lane(h[j], u);
                wa[j] += s*w2.x; wb[j] += s*w2.y;
            }
        }

        // ---- uvu (registers) -> km planes in LDS ----
        #pragma unroll
        for (int j = 0; j < 4; ++j){
            const int eb = sb + j*272;
            const float* ya = eattr + (size_t)(e0+j)*4;
            float y0 = ya[0], y1a = ya[1], y1b = ya[2], y1c = ya[3];
            const float* fp = feats + (size_t)src[j]*128 + xsi;
            float xa = fp[0], xb = fp[1], xc = fp[2];

            float wA = low ? wa[j] : wb[j];
            float wB = low ? wb[j] : wa[j];

            float dotv = xa*y1a + xb*y1b + xc*y1c;
            float km0 = wA * (low ? xa*y0 : dotv*INV_SQRT3);
            float pm  = wB * (low ? xa : y0);
            float t0  = low ? y1a : xa, t1 = low ? y1b : xb, t2 = low ? y1c : xc;
            lds[eb +       lane] = km0;
            lds[eb + 68  + lane] = pm*t0;
            lds[eb + 136 + lane] = pm*t1;
            lds[eb + 204 + lane] = pm*t2;
        }

        // ---- lin: k = lin(km)/8; b128 plane reads, wts from L1 ----
        float l0[4] = {0,0,0,0}, l1[4] = {0,0,0,0};
        #pragma unroll
        for (int u4 = 0; u4 < 16; ++u4){
            float2 wz0 = *(const float2*)&wlin[(u4*4+0)*32];
            float2 wz1 = *(const float2*)&wlin[(u4*4+1)*32];
            float2 wz2 = *(const float2*)&wlin[(u4*4+2)*32];
            float2 wz3 = *(const float2*)&wlin[(u4*4+3)*32];
            #pragma unroll
            for (int j = 0; j < 4; ++j){
                float4 m = *(const float4*)&lds[sb + j*272 + poff + u4*4];
                l0[j] += m.x*wz0.x + m.y*wz1.x + m.z*wz2.x + m.w*wz3.x;
                l1[j] += m.x*wz0.y + m.y*wz1.y + m.z*wz2.y + m.w*wz3.y;
            }
        }

        // ---- d: part = k.qd[dst] (all scales folded); shfl reduce ----
        #pragma unroll
        for (int j = 0; j < 4; ++j){
            const float* qdp = qdbuf + (size_t)dst[j]*128;
            float part = (l0[j]*qdp[o0] + l1[j]*qdp[o1]) * 0.125f;
            #pragma unroll
            for (int off = 32; off > 0; off >>= 1)
                part += __shfl_xor(part, off);
            if (lane == 0){
                // cutoff const: diff = pos[src]-pos[src] == 0 (reference bug)
                float ev = 0.9048374180359595f * expf(part);
                expv_buf[e0+j] = ev;
                atomicAdd(&zbuf[dst[j]], ev);
            }
        }
    }
}

__global__ __launch_bounds__(256, 3) void edge_pass2(
    const float* __restrict__ feats, const float* __restrict__ emb,
    const float* __restrict__ eattr, const int* __restrict__ eidx,
    const float* __restrict__ Wv1, const float* __restrict__ Wv2,
    const float* __restrict__ Wlv0, const float* __restrict__ Wlv1,
    const float* __restrict__ expv_buf, const float* __restrict__ zbuf,
    float* __restrict__ out)
{
    __shared__ float lds[12544];
    const int t    = threadIdx.x;
    const int lane = t & 63;
    const bool low = lane < 32;
    const int c1 = low ? lane : lane + 32;
    const int c2 = c1 + 32;

    {
        const int wvz = t >> 6;
        for (int u = wvz; u < 64; u += 4){
            lds[(u*64+lane)*2+0] = Wv2[u*128 + c1] * 0.125f;
            lds[(u*64+lane)*2+1] = Wv2[u*128 + c2] * 0.125f;
        }
    }
    float wk1r[16];
    #pragma unroll
    for (int a = 0; a < 16; ++a) wk1r[a] = Wv1[a*64 + lane] * 0.25f;
    __syncthreads();

    const int wv = __builtin_amdgcn_readfirstlane(t >> 6);
    const int sb = 8192 + wv*1088;

    const int p  = lane >> 4;
    const int v0 = (2*lane) & 31;
    const float* __restrict__ wlin = ((p==0)? Wlv0 : Wlv1) + v0;
    const int poff = (p==0)? 0 : (68 + (p-1)*68);
    const int o0 = (p==0)? v0     : 32 + v0*3     + (p-1);
    const int o1 = (p==0)? v0 + 1 : 32 + (v0+1)*3 + (p-1);

    const int xsi = low ? lane : (32 + 3*(lane-32));
    const int ebase = (blockIdx.x*4 + wv) * 64;

    for (int it = 0; it < 16; ++it){
        const int e0 = __builtin_amdgcn_readfirstlane(ebase + 4*it);
        int src[4], dst[4];
        #pragma unroll
        for (int j = 0; j < 4; ++j){
            src[j] = eidx[e0+j]; dst[j] = eidx[N_EDGES+e0+j];
        }

        float h[4];
        #pragma unroll
        for (int j = 0; j < 4; ++j){
            const float4* em = (const float4*)(emb + (size_t)(e0+j)*16);
            float acc = 0.f;
            #pragma unroll
            for (int a4 = 0; a4 < 4; ++a4){
                float4 v = em[a4];
                acc += v.x*wk1r[a4*4+0] + v.y*wk1r[a4*4+1]
                     + v.z*wk1r[a4*4+2] + v.w*wk1r[a4*4+3];
            }
            h[j] = sspf(acc);
        }

        float wa[4] = {0,0,0,0}, wb[4] = {0,0,0,0};
        #pragma unroll
        for (int u = 0; u < 64; ++u){
            float2 w2 = *(const float2*)&lds[(u*64+lane)*2];
            #pragma unroll
            for (int j = 0; j < 4; ++j){
                float s = bcast_lane(h[j], u);
                wa[j] += s*w2.x; wb[j] += s*w2.y;
            }
        }

        #pragma unroll
        for (int j = 0; j < 4; ++j){
            const int eb = sb + j*272;
            const float* ya = eattr + (size_t)(e0+j)*4;
            float y0 = ya[0], y1a = ya[1], y1b = ya[2], y1c = ya[3];
            const float* fp = feats + (size_t)src[j]*128 + xsi;
            float xa = fp[0], xb = fp[1], xc = fp[2];

            float wA = low ? wa[j] : wb[j];
            float wB = low ? wb[j] : wa[j];

            float dotv = xa*y1a + xb*y1b + xc*y1c;
            float km0 = wA * (low ? xa*y0 : dotv*INV_SQRT3);
            float pm  = wB * (low ? xa : y0);
            float t0  = low ? y1a : xa, t1 = low ? y1b : xb, t2 = low ? y1c : xc;
            lds[eb +       lane] = km0;
            lds[eb + 68  + lane] = pm*t0;
            lds[eb + 136 + lane] = pm*t1;
            lds[eb + 204 + lane] = pm*t2;
        }

        float l0[4] = {0,0,0,0}, l1[4] = {0,0,0,0};
        #pragma unroll
        for (int u4 = 0; u4 < 16; ++u4){
            float2 wz0 = *(const float2*)&wlin[(u4*4+0)*32];
            float2 wz1 = *(const float2*)&wlin[(u4*4+1)*32];
            float2 wz2 = *(const float2*)&wlin[(u4*4+2)*32];
            float2 wz3 = *(const float2*)&wlin[(u4*4+3)*32];
            #pragma unroll
            for (int j = 0; j < 4; ++j){
                float4 m = *(const float4*)&lds[sb + j*272 + poff + u4*4];
                l0[j] += m.x*wz0.x + m.y*wz1.x + m.z*wz2.x + m.w*wz3.x;
                l1[j] += m.x*wz0.y + m.y*wz1.y + m.z*wz2.y + m.w*wz3.y;
            }
        }

        // ---- epilogue: coef = sqrt(relu(alpha)); atomic scatter-add ----
        #pragma unroll
        for (int j = 0; j < 4; ++j){
            float ev = expv_buf[e0+j];
            float zz = zbuf[dst[j]];
            zz = (zz == 0.f) ? 1.f : zz;
            float coef = sqrtf(fmaxf(ev/zz, 0.f)) * 0.125f;
            float* op = out + (size_t)dst[j]*128;
            atomicAdd(op + o0, coef*l0[j]);
            atomicAdd(op + o1, coef*l1[j]);
        }
    }
}

extern "C" void kernel_launch(void* const* d_in, const int* in_sizes, int n_in,
                              void* d_out, int out_size, void* d_ws, size_t ws_size,
                              hipStream_t stream)
{
    const float* feats = (const float*)d_in[0];
    const float* attrs = (const float*)d_in[1];
    const float* emb   = (const float*)d_in[2];
    const float* eattr = (const float*)d_in[3];
    // d_in[4] positions: unused (reference computes positions[src]-positions[src] == 0)
    const float* Wq0  = (const float*)d_in[5];
    const float* Wq1  = (const float*)d_in[6];
    const float* Wk1  = (const float*)d_in[7];
    const float* Wk2  = (const float*)d_in[8];
    const float* Wv1  = (const float*)d_in[9];
    const float* Wv2  = (const float*)d_in[10];
    const float* Wlk0 = (const float*)d_in[11];
    const float* Wlk1 = (const float*)d_in[12];
    const float* Wlv0 = (const float*)d_in[13];
    const float* Wlv1 = (const float*)d_in[14];
    const float* Wd0  = (const float*)d_in[15];
    const float* Wd1  = (const float*)d_in[16];
    const float* Ws0  = (const float*)d_in[17];
    const float* Ws1  = (const float*)d_in[18];
    const int*   eidx = (const int*)d_in[19];

    float* out   = (float*)d_out;
    float* qdbuf = (float*)d_ws;                  // N*128 floats (qd = Wd^T q, scaled)
    float* expv  = qdbuf + (size_t)N_NODES*128;   // E floats
    float* zbuf  = expv + (size_t)N_EDGES;        // N floats

    hipMemsetAsync(zbuf, 0, N_NODES*sizeof(float), stream);
    node_kernel<<<N_NODES, 128, 0, stream>>>(feats, attrs, Wq0, Wq1, Wd0, Wd1,
                                             Ws0, Ws1, qdbuf, out);
    edge_pass1<<<N_EDGES/256, 256, 0, stream>>>(feats, emb, eattr, eidx,
                                                Wk1, Wk2, Wlk0, Wlk1,
                                                qdbuf, expv, zbuf);
    edge_pass2<<<N_EDGES/256, 256, 0, stream>>>(feats, emb, eattr, eidx,
                                                Wv1, Wv2, Wlv0, Wlv1,
                                                expv, zbuf, out);
}

// Round 6
// 879.144 us; speedup vs baseline: 3.3248x; 3.3248x over previous
//
#include <hip/hip_runtime.h>
#include <math.h>

#define N_NODES 8192
#define N_EDGES 262144
#define INV_SQRT3 0.5773502691896258f

__device__ __forceinline__ float sspf(float x){
    // softplus(x) - ln(2), numerically stable
    float sp = (x > 20.0f) ? x : log1pf(expf(x));
    return sp - 0.6931471805599453f;
}

__device__ __forceinline__ float bcast_lane(float v, int u){
    return __uint_as_float(__builtin_amdgcn_readlane(__float_as_uint(v), u));
}

// ---------------------------------------------------------------------------
// Kernel A: per-node: out = sc (self-connection);
// qd = Wd^T q with all d-stage scales folded in:
//   qd0[v]    = (1/sqrt(2048))       * sum_u q0[u]    * Wd0[u][v]
//   qd1[v][c] = (1/sqrt(2048)/sqrt3)* sum_u q1[u][c] * Wd1[u][v]
// qd layout per node (128): qd0[0..31], qd1 at 32+v*3+c  (matches k layout)
// ---------------------------------------------------------------------------
__global__ __launch_bounds__(128) void node_kernel(
    const float* __restrict__ feats, const float* __restrict__ attrs,
    const float* __restrict__ Wq0, const float* __restrict__ Wq1,
    const float* __restrict__ Wd0, const float* __restrict__ Wd1,
    const float* __restrict__ Ws0, const float* __restrict__ Ws1,
    float* __restrict__ qdbuf, float* __restrict__ out)
{
    int n = blockIdx.x; int t = threadIdx.x;
    __shared__ float sf[128];
    __shared__ float sa[16];
    __shared__ float sq[128];
    sf[t] = feats[n*128 + t];
    if (t < 16) sa[t] = attrs[n*16 + t];
    __syncthreads();
    const float inv_sqrt32 = 0.17677669529663687f;   // 1/sqrt(32)
    const float sc_scale   = 0.04419417382415922f;   // 1/sqrt(32*16)
    const float d_scale    = 0.022097086912079608f;  // 1/sqrt(2*32*32)
    float qv, scv;
    if (t < 32){
        int v = t;
        float acc = 0.f;
        for (int u = 0; u < 32; ++u) acc += sf[u] * Wq0[u*32 + v];
        qv = acc * inv_sqrt32;
        acc = 0.f;
        for (int u = 0; u < 32; ++u){
            float su = sf[u];
            for (int a = 0; a < 16; ++a)
                acc += su * sa[a] * Ws0[(u*16 + a)*32 + v];
        }
        scv = acc * sc_scale;
    } else {
        int k = t - 32; int v = k/3; int c = k - v*3;
        float acc = 0.f;
        for (int u = 0; u < 32; ++u) acc += sf[32 + u*3 + c] * Wq1[u*32 + v];
        qv = acc * inv_sqrt32;
        acc = 0.f;
        for (int u = 0; u < 32; ++u){
            float su = sf[32 + u*3 + c];
            for (int a = 0; a < 16; ++a)
                acc += su * sa[a] * Ws1[(u*16 + a)*32 + v];
        }
        scv = acc * sc_scale;
    }
    sq[t] = qv;
    out[n*128 + t] = scv;
    __syncthreads();

    float qd;
    if (t < 32){
        int v = t;
        float acc = 0.f;
        for (int u = 0; u < 32; ++u) acc += sq[u] * Wd0[u*32 + v];
        qd = acc * d_scale;
    } else {
        int k = t - 32; int v = k/3; int c = k - v*3;
        float acc = 0.f;
        for (int u = 0; u < 32; ++u) acc += sq[32 + u*3 + c] * Wd1[u*32 + v];
        qd = acc * d_scale * INV_SQRT3;
    }
    qdbuf[n*128 + t] = qd;
}

// ---------------------------------------------------------------------------
// Edge passes: 2 edges per wave-iteration, 64 edges per wave.
// All per-edge state is EXPLICIT SCALARS (no indexable arrays -> no scratch
// demotion; R4/R5 post-mortem: arrays in big loops became scratch traffic).
// LDS (10368 dwords = 41472 B -> 3 blocks/CU):
//   W2 permuted+prescaled @ 0 (8192): [u][lane] -> {W2[u][c1],W2[u][c2]}*.125
//   scratch @ 8192: 4 waves x 2 edges x 272 dwords; km planes at +0/68/136/204
//     (lin b128 reads are uniform within each 16-lane p-group -> broadcast)
// h kept in registers, broadcast via v_readlane. qd-precompute kills d-stage
// LDS. No per-iteration barriers (scratch is per-wave; same-wave DS in-order).
// ---------------------------------------------------------------------------
__global__ __launch_bounds__(256) void edge_pass1(
    const float* __restrict__ feats, const float* __restrict__ emb,
    const float* __restrict__ eattr, const int* __restrict__ eidx,
    const float* __restrict__ Wk1, const float* __restrict__ Wk2,
    const float* __restrict__ Wlk0, const float* __restrict__ Wlk1,
    const float* __restrict__ qdbuf,
    float* __restrict__ expv_buf, float* __restrict__ zbuf)
{
    __shared__ float lds[10368];
    const int t    = threadIdx.x;
    const int lane = t & 63;
    const bool low = lane < 32;
    const int c1 = low ? lane : lane + 32;   // owned GEMM2 output cols
    const int c2 = c1 + 32;

    {   // permuted + prescaled W2 preload (all 4 waves cooperate)
        const int wvz = t >> 6;
        for (int u = wvz; u < 64; u += 4){
            lds[(u*64+lane)*2+0] = Wk2[u*128 + c1] * 0.125f;
            lds[(u*64+lane)*2+1] = Wk2[u*128 + c2] * 0.125f;
        }
    }
    float wk1r[16];
    #pragma unroll
    for (int a = 0; a < 16; ++a) wk1r[a] = Wk1[a*64 + lane] * 0.25f;
    __syncthreads();   // the only barrier

    const int wv  = __builtin_amdgcn_readfirstlane(t >> 6);
    const int sb0 = 8192 + wv*544;           // wave scratch: 2 edges x 272
    const int sb1 = sb0 + 272;

    // lin-stage lane constants: lane owns outputs o0,o1
    const int p  = lane >> 4;                // 0..3
    const int v0 = (2*lane) & 31;
    const float* __restrict__ wlin = ((p==0)? Wlk0 : Wlk1) + v0;
    const int poff = (p==0)? 0 : (68 + (p-1)*68);   // 0,68,136,204
    const int o0 = (p==0)? v0     : 32 + v0*3     + (p-1);
    const int o1 = (p==0)? v0 + 1 : 32 + (v0+1)*3 + (p-1);

    const int xsi = low ? lane : (32 + 3*(lane-32));
    const int ebase = (blockIdx.x*4 + wv) * 64;

    for (int it = 0; it < 32; ++it){
        const int e0 = __builtin_amdgcn_readfirstlane(ebase + 2*it);
        const int e1 = e0 + 1;
        const int src0 = eidx[e0], dst0 = eidx[N_EDGES+e0];
        const int src1 = eidx[e1], dst1 = eidx[N_EDGES+e1];

        // ---- GEMM1: h = ssp(emb@Wk1/4), per edge, in registers ----
        float h0 = 0.f, h1 = 0.f;
        {
            const float4* em0 = (const float4*)(emb + (size_t)e0*16);
            const float4* em1 = (const float4*)(emb + (size_t)e1*16);
            #pragma unroll
            for (int a4 = 0; a4 < 4; ++a4){
                float4 va = em0[a4], vb = em1[a4];
                h0 += va.x*wk1r[a4*4+0] + va.y*wk1r[a4*4+1]
                    + va.z*wk1r[a4*4+2] + va.w*wk1r[a4*4+3];
                h1 += vb.x*wk1r[a4*4+0] + vb.y*wk1r[a4*4+1]
                    + vb.z*wk1r[a4*4+2] + vb.w*wk1r[a4*4+3];
            }
            h0 = sspf(h0); h1 = sspf(h1);
        }

        // ---- GEMM2: w = h@Wk2/8; b64 LDS weights shared over 2 edges,
        //      h broadcast via readlane; explicit scalar accumulators ----
        float wa0=0.f, wb0=0.f, wa1=0.f, wb1=0.f;
        #pragma unroll 8
        for (int u = 0; u < 64; ++u){
            float2 w2 = *(const float2*)&lds[(u*64+lane)*2];
            float s0 = bcast_lane(h0, u);
            float s1 = bcast_lane(h1, u);
            wa0 += s0*w2.x; wb0 += s0*w2.y;
            wa1 += s1*w2.x; wb1 += s1*w2.y;
        }

        // ---- uvu (registers) -> km planes in LDS ----
        {
            const float* ya = eattr + (size_t)e0*4;
            float y0 = ya[0], y1a = ya[1], y1b = ya[2], y1c = ya[3];
            const float* fp = feats + (size_t)src0*128 + xsi;
            float xa = fp[0], xb = fp[1], xc = fp[2];
            float wA = low ? wa0 : wb0;
            float wB = low ? wb0 : wa0;
            float dotv = xa*y1a + xb*y1b + xc*y1c;
            float km0 = wA * (low ? xa*y0 : dotv*INV_SQRT3);
            float pm  = wB * (low ? xa : y0);
            float t0  = low ? y1a : xa, t1 = low ? y1b : xb, t2 = low ? y1c : xc;
            lds[sb0 +       lane] = km0;
            lds[sb0 + 68  + lane] = pm*t0;
            lds[sb0 + 136 + lane] = pm*t1;
            lds[sb0 + 204 + lane] = pm*t2;
        }
        {
            const float* ya = eattr + (size_t)e1*4;
            float y0 = ya[0], y1a = ya[1], y1b = ya[2], y1c = ya[3];
            const float* fp = feats + (size_t)src1*128 + xsi;
            float xa = fp[0], xb = fp[1], xc = fp[2];
            float wA = low ? wa1 : wb1;
            float wB = low ? wb1 : wa1;
            float dotv = xa*y1a + xb*y1b + xc*y1c;
            float km0 = wA * (low ? xa*y0 : dotv*INV_SQRT3);
            float pm  = wB * (low ? xa : y0);
            float t0  = low ? y1a : xa, t1 = low ? y1b : xb, t2 = low ? y1c : xc;
            lds[sb1 +       lane] = km0;
            lds[sb1 + 68  + lane] = pm*t0;
            lds[sb1 + 136 + lane] = pm*t1;
            lds[sb1 + 204 + lane] = pm*t2;
        }

        // ---- lin: k = lin(km)/8; b128 plane reads (p-group broadcast) ----
        float l00=0.f,l01=0.f,l10=0.f,l11=0.f;
        #pragma unroll
        for (int u4 = 0; u4 < 16; ++u4){
            float4 m0 = *(const float4*)&lds[sb0 + poff + u4*4];
            float4 m1 = *(const float4*)&lds[sb1 + poff + u4*4];
            float2 wz0 = *(const float2*)&wlin[(u4*4+0)*32];
            float2 wz1 = *(const float2*)&wlin[(u4*4+1)*32];
            float2 wz2 = *(const float2*)&wlin[(u4*4+2)*32];
            float2 wz3 = *(const float2*)&wlin[(u4*4+3)*32];
            l00 += m0.x*wz0.x + m0.y*wz1.x + m0.z*wz2.x + m0.w*wz3.x;
            l01 += m0.x*wz0.y + m0.y*wz1.y + m0.z*wz2.y + m0.w*wz3.y;
            l10 += m1.x*wz0.x + m1.y*wz1.x + m1.z*wz2.x + m1.w*wz3.x;
            l11 += m1.x*wz0.y + m1.y*wz1.y + m1.z*wz2.y + m1.w*wz3.y;
        }

        // ---- d: part = k.qd[dst] (all scales folded); shfl reduce ----
        {
            const float* qdp0 = qdbuf + (size_t)dst0*128;
            const float* qdp1 = qdbuf + (size_t)dst1*128;
            float part0 = (l00*qdp0[o0] + l01*qdp0[o1]) * 0.125f;
            float part1 = (l10*qdp1[o0] + l11*qdp1[o1]) * 0.125f;
            #pragma unroll
            for (int off = 32; off > 0; off >>= 1){
                part0 += __shfl_xor(part0, off);
                part1 += __shfl_xor(part1, off);
            }
            if (lane == 0){
                // cutoff const: diff = pos[src]-pos[src] == 0 (reference bug)
                float ev0 = 0.9048374180359595f * expf(part0);
                float ev1 = 0.9048374180359595f * expf(part1);
                expv_buf[e0] = ev0;
                expv_buf[e1] = ev1;
                atomicAdd(&zbuf[dst0], ev0);
                atomicAdd(&zbuf[dst1], ev1);
            }
        }
    }
}

__global__ __launch_bounds__(256) void edge_pass2(
    const float* __restrict__ feats, const float* __restrict__ emb,
    const float* __restrict__ eattr, const int* __restrict__ eidx,
    const float* __restrict__ Wv1, const float* __restrict__ Wv2,
    const float* __restrict__ Wlv0, const float* __restrict__ Wlv1,
    const float* __restrict__ expv_buf, const float* __restrict__ zbuf,
    float* __restrict__ out)
{
    __shared__ float lds[10368];
    const int t    = threadIdx.x;
    const int lane = t & 63;
    const bool low = lane < 32;
    const int c1 = low ? lane : lane + 32;
    const int c2 = c1 + 32;

    {
        const int wvz = t >> 6;
        for (int u = wvz; u < 64; u += 4){
            lds[(u*64+lane)*2+0] = Wv2[u*128 + c1] * 0.125f;
            lds[(u*64+lane)*2+1] = Wv2[u*128 + c2] * 0.125f;
        }
    }
    float wk1r[16];
    #pragma unroll
    for (int a = 0; a < 16; ++a) wk1r[a] = Wv1[a*64 + lane] * 0.25f;
    __syncthreads();

    const int wv  = __builtin_amdgcn_readfirstlane(t >> 6);
    const int sb0 = 8192 + wv*544;
    const int sb1 = sb0 + 272;

    const int p  = lane >> 4;
    const int v0 = (2*lane) & 31;
    const float* __restrict__ wlin = ((p==0)? Wlv0 : Wlv1) + v0;
    const int poff = (p==0)? 0 : (68 + (p-1)*68);
    const int o0 = (p==0)? v0     : 32 + v0*3     + (p-1);
    const int o1 = (p==0)? v0 + 1 : 32 + (v0+1)*3 + (p-1);

    const int xsi = low ? lane : (32 + 3*(lane-32));
    const int ebase = (blockIdx.x*4 + wv) * 64;

    for (int it = 0; it < 32; ++it){
        const int e0 = __builtin_amdgcn_readfirstlane(ebase + 2*it);
        const int e1 = e0 + 1;
        const int src0 = eidx[e0], dst0 = eidx[N_EDGES+e0];
        const int src1 = eidx[e1], dst1 = eidx[N_EDGES+e1];

        float h0 = 0.f, h1 = 0.f;
        {
            const float4* em0 = (const float4*)(emb + (size_t)e0*16);
            const float4* em1 = (const float4*)(emb + (size_t)e1*16);
            #pragma unroll
            for (int a4 = 0; a4 < 4; ++a4){
                float4 va = em0[a4], vb = em1[a4];
                h0 += va.x*wk1r[a4*4+0] + va.y*wk1r[a4*4+1]
                    + va.z*wk1r[a4*4+2] + va.w*wk1r[a4*4+3];
                h1 += vb.x*wk1r[a4*4+0] + vb.y*wk1r[a4*4+1]
                    + vb.z*wk1r[a4*4+2] + vb.w*wk1r[a4*4+3];
            }
            h0 = sspf(h0); h1 = sspf(h1);
        }

        float wa0=0.f, wb0=0.f, wa1=0.f, wb1=0.f;
        #pragma unroll 8
        for (int u = 0; u < 64; ++u){
            float2 w2 = *(const float2*)&lds[(u*64+lane)*2];
            float s0 = bcast_lane(h0, u);
            float s1 = bcast_lane(h1, u);
            wa0 += s0*w2.x; wb0 += s0*w2.y;
            wa1 += s1*w2.x; wb1 += s1*w2.y;
        }

        {
            const float* ya = eattr + (size_t)e0*4;
            float y0 = ya[0], y1a = ya[1], y1b = ya[2], y1c = ya[3];
            const float* fp = feats + (size_t)src0*128 + xsi;
            float xa = fp[0], xb = fp[1], xc = fp[2];
            float wA = low ? wa0 : wb0;
            float wB = low ? wb0 : wa0;
            float dotv = xa*y1a + xb*y1b + xc*y1c;
            float km0 = wA * (low ? xa*y0 : dotv*INV_SQRT3);
            float pm  = wB * (low ? xa : y0);
            float t0  = low ? y1a : xa, t1 = low ? y1b : xb, t2 = low ? y1c : xc;
            lds[sb0 +       lane] = km0;
            lds[sb0 + 68  + lane] = pm*t0;
            lds[sb0 + 136 + lane] = pm*t1;
            lds[sb0 + 204 + lane] = pm*t2;
        }
        {
            const float* ya = eattr + (size_t)e1*4;
            float y0 = ya[0], y1a = ya[1], y1b = ya[2], y1c = ya[3];
            const float* fp = feats + (size_t)src1*128 + xsi;
            float xa = fp[0], xb = fp[1], xc = fp[2];
            float wA = low ? wa1 : wb1;
            float wB = low ? wb1 : wa1;
            float dotv = xa*y1a + xb*y1b + xc*y1c;
            float km0 = wA * (low ? xa*y0 : dotv*INV_SQRT3);
            float pm  = wB * (low ? xa : y0);
            float t0  = low ? y1a : xa, t1 = low ? y1b : xb, t2 = low ? y1c : xc;
            lds[sb1 +       lane] = km0;
            lds[sb1 + 68  + lane] = pm*t0;
            lds[sb1 + 136 + lane] = pm*t1;
            lds[sb1 + 204 + lane] = pm*t2;
        }

        float l00=0.f,l01=0.f,l10=0.f,l11=0.f;
        #pragma unroll
        for (int u4 = 0; u4 < 16; ++u4){
            float4 m0 = *(const float4*)&lds[sb0 + poff + u4*4];
            float4 m1 = *(const float4*)&lds[sb1 + poff + u4*4];
            float2 wz0 = *(const float2*)&wlin[(u4*4+0)*32];
            float2 wz1 = *(const float2*)&wlin[(u4*4+1)*32];
            float2 wz2 = *(const float2*)&wlin[(u4*4+2)*32];
            float2 wz3 = *(const float2*)&wlin[(u4*4+3)*32];
            l00 += m0.x*wz0.x + m0.y*wz1.x + m0.z*wz2.x + m0.w*wz3.x;
            l01 += m0.x*wz0.y + m0.y*wz1.y + m0.z*wz2.y + m0.w*wz3.y;
            l10 += m1.x*wz0.x + m1.y*wz1.x + m1.z*wz2.x + m1.w*wz3.x;
            l11 += m1.x*wz0.y + m1.y*wz1.y + m1.z*wz2.y + m1.w*wz3.y;
        }

        // ---- epilogue: coef = sqrt(relu(alpha)); atomic scatter-add ----
        {
            float ev0 = expv_buf[e0];
            float zz0 = zbuf[dst0];
            zz0 = (zz0 == 0.f) ? 1.f : zz0;
            float coef0 = sqrtf(fmaxf(ev0/zz0, 0.f)) * 0.125f;
            float* op0 = out + (size_t)dst0*128;
            atomicAdd(op0 + o0, coef0*l00);
            atomicAdd(op0 + o1, coef0*l01);

            float ev1 = expv_buf[e1];
            float zz1 = zbuf[dst1];
            zz1 = (zz1 == 0.f) ? 1.f : zz1;
            float coef1 = sqrtf(fmaxf(ev1/zz1, 0.f)) * 0.125f;
            float* op1 = out + (size_t)dst1*128;
            atomicAdd(op1 + o0, coef1*l10);
            atomicAdd(op1 + o1, coef1*l11);
        }
    }
}

extern "C" void kernel_launch(void* const* d_in, const int* in_sizes, int n_in,
                              void* d_out, int out_size, void* d_ws, size_t ws_size,
                              hipStream_t stream)
{
    const float* feats = (const float*)d_in[0];
    const float* attrs = (const float*)d_in[1];
    const float* emb   = (const float*)d_in[2];
    const float* eattr = (const float*)d_in[3];
    // d_in[4] positions: unused (reference computes positions[src]-positions[src] == 0)
    const float* Wq0  = (const float*)d_in[5];
    const float* Wq1  = (const float*)d_in[6];
    const float* Wk1  = (const float*)d_in[7];
    const float* Wk2  = (const float*)d_in[8];
    const float* Wv1  = (const float*)d_in[9];
    const float* Wv2  = (const float*)d_in[10];
    const float* Wlk0 = (const float*)d_in[11];
    const float* Wlk1 = (const float*)d_in[12];
    const float* Wlv0 = (const float*)d_in[13];
    const float* Wlv1 = (const float*)d_in[14];
    const float* Wd0  = (const float*)d_in[15];
    const float* Wd1  = (const float*)d_in[16];
    const float* Ws0  = (const float*)d_in[17];
    const float* Ws1  = (const float*)d_in[18];
    const int*   eidx = (const int*)d_in[19];

    float* out   = (float*)d_out;
    float* qdbuf = (float*)d_ws;                  // N*128 floats (qd = Wd^T q, scaled)
    float* expv  = qdbuf + (size_t)N_NODES*128;   // E floats
    float* zbuf  = expv + (size_t)N_EDGES;        // N floats

    hipMemsetAsync(zbuf, 0, N_NODES*sizeof(float), stream);
    node_kernel<<<N_NODES, 128, 0, stream>>>(feats, attrs, Wq0, Wq1, Wd0, Wd1,
                                             Ws0, Ws1, qdbuf, out);
    edge_pass1<<<N_EDGES/256, 256, 0, stream>>>(feats, emb, eattr, eidx,
                                                Wk1, Wk2, Wlk0, Wlk1,
                                                qdbuf, expv, zbuf);
    edge_pass2<<<N_EDGES/256, 256, 0, stream>>>(feats, emb, eattr, eidx,
                                                Wv1, Wv2, Wlv0, Wlv1,
                                                expv, zbuf, out);
}

// Round 7
// 607.067 us; speedup vs baseline: 4.8149x; 1.4482x over previous
//
#include <hip/hip_runtime.h>
#include <math.h>

#define N_NODES 8192
#define N_EDGES 262144
#define INV_SQRT3 0.5773502691896258f

typedef __attribute__((ext_vector_type(8))) _Float16 half8;
typedef __attribute__((ext_vector_type(4))) float floatx4;

#define MF16(a,b,c) __builtin_amdgcn_mfma_f32_16x16x32_f16(a,b,c,0,0,0)

__device__ __forceinline__ float sspf(float x){
    // softplus(x) - ln(2), numerically stable
    float sp = (x > 20.0f) ? x : log1pf(expf(x));
    return sp - 0.6931471805599453f;
}

// ---------------------------------------------------------------------------
// Kernel A: per-node: out = sc (self-connection);
// qd = Wd^T q with all d-stage scales folded in. qd layout per node (128):
// qd0[0..31], qd1 at 32+v*3+c (matches k/out layout).
// ---------------------------------------------------------------------------
__global__ __launch_bounds__(128) void node_kernel(
    const float* __restrict__ feats, const float* __restrict__ attrs,
    const float* __restrict__ Wq0, const float* __restrict__ Wq1,
    const float* __restrict__ Wd0, const float* __restrict__ Wd1,
    const float* __restrict__ Ws0, const float* __restrict__ Ws1,
    float* __restrict__ qdbuf, float* __restrict__ out)
{
    int n = blockIdx.x; int t = threadIdx.x;
    __shared__ float sf[128];
    __shared__ float sa[16];
    __shared__ float sq[128];
    sf[t] = feats[n*128 + t];
    if (t < 16) sa[t] = attrs[n*16 + t];
    __syncthreads();
    const float inv_sqrt32 = 0.17677669529663687f;   // 1/sqrt(32)
    const float sc_scale   = 0.04419417382415922f;   // 1/sqrt(32*16)
    const float d_scale    = 0.022097086912079608f;  // 1/sqrt(2*32*32)
    float qv, scv;
    if (t < 32){
        int v = t;
        float acc = 0.f;
        for (int u = 0; u < 32; ++u) acc += sf[u] * Wq0[u*32 + v];
        qv = acc * inv_sqrt32;
        acc = 0.f;
        for (int u = 0; u < 32; ++u){
            float su = sf[u];
            for (int a = 0; a < 16; ++a)
                acc += su * sa[a] * Ws0[(u*16 + a)*32 + v];
        }
        scv = acc * sc_scale;
    } else {
        int k = t - 32; int v = k/3; int c = k - v*3;
        float acc = 0.f;
        for (int u = 0; u < 32; ++u) acc += sf[32 + u*3 + c] * Wq1[u*32 + v];
        qv = acc * inv_sqrt32;
        acc = 0.f;
        for (int u = 0; u < 32; ++u){
            float su = sf[32 + u*3 + c];
            for (int a = 0; a < 16; ++a)
                acc += su * sa[a] * Ws1[(u*16 + a)*32 + v];
        }
        scv = acc * sc_scale;
    }
    sq[t] = qv;
    out[n*128 + t] = scv;
    __syncthreads();

    float qd;
    if (t < 32){
        int v = t;
        float acc = 0.f;
        for (int u = 0; u < 32; ++u) acc += sq[u] * Wd0[u*32 + v];
        qd = acc * d_scale;
    } else {
        int k = t - 32; int v = k/3; int c = k - v*3;
        float acc = 0.f;
        for (int u = 0; u < 32; ++u) acc += sq[32 + u*3 + c] * Wd1[u*32 + v];
        qd = acc * d_scale * INV_SQRT3;
    }
    qdbuf[n*128 + t] = qd;
}

// ---------------------------------------------------------------------------
// MFMA edge kernel (PASS=1: k-path -> expv/z; PASS=2: v-path -> atomic out).
// One wave processes 16 edges per iteration (M=16 MFMA tiles), 4 iterations.
// mfma_f32_16x16x32_f16 layouts (measured, learn_hip m89/m120):
//   A[m=lane&15][k=quad*8+j]; B[k=quad*8+j][n=lane&15]; C col=lane&15,
//   row=quad*4+reg.
// Weight B-fragments pre-swizzled into LDS fp16 with scales folded.
// h and w round-trip LDS per-wave (no barriers in main loop).
// km computed directly in A-frag layout -> stays in registers.
// All unrolled loops have compile-time-constant indices (no scratch demotion).
// ---------------------------------------------------------------------------
template<int PASS>
__global__ __launch_bounds__(256) void edge_mfma(
    const float* __restrict__ feats, const float* __restrict__ emb,
    const float* __restrict__ eattr, const int* __restrict__ eidx,
    const float* __restrict__ W1,  const float* __restrict__ W2,
    const float* __restrict__ WL0, const float* __restrict__ WL1,
    const float* __restrict__ qdbuf,
    float* __restrict__ expv_buf, float* __restrict__ zbuf,
    float* __restrict__ out)
{
    __shared__ half8 fW1[4][64];        //  4 KB
    __shared__ half8 fW2[16][64];       // 16 KB
    __shared__ half8 fL0[4][64];        //  4 KB
    __shared__ half8 fL1[4][64];        //  4 KB
    __shared__ _Float16 hbuf[4][16][72];   // padded rows (bank spread)
    __shared__ _Float16 wbuf[4][16][136];

    const int t    = threadIdx.x;
    const int lane = t & 63;
    const int col  = lane & 15;
    const int quad = lane >> 4;
    const int g    = t >> 6;            // wave id, also preload group

    // ---- preload weight fragments (scales folded) ----
    {
        half8 f;
        #pragma unroll
        for (int j = 0; j < 8; ++j){
            int k = quad*8 + j;
            f[j] = (k < 16) ? (_Float16)(W1[k*64 + g*16 + col] * 0.25f)
                            : (_Float16)0.f;
        }
        fW1[g][lane] = f;
    }
    #pragma unroll
    for (int ff = 0; ff < 4; ++ff){
        int fr = g*4 + ff, tile = fr >> 1, s = fr & 1;
        half8 f;
        #pragma unroll
        for (int j = 0; j < 8; ++j)
            f[j] = (_Float16)(W2[(s*32 + quad*8 + j)*128 + tile*16 + col] * 0.125f);
        fW2[fr][lane] = f;
    }
    {
        int tile = g >> 1, s = g & 1;
        half8 f0, f1;
        #pragma unroll
        for (int j = 0; j < 8; ++j){
            int k = s*32 + quad*8 + j;
            f0[j] = (_Float16)(WL0[k*32 + tile*16 + col] * 0.125f);
            f1[j] = (_Float16)(WL1[k*32 + tile*16 + col] * 0.125f);
        }
        fL0[g][lane] = f0; fL1[g][lane] = f1;
    }
    __syncthreads();     // the only block-wide barrier

    const floatx4 zz = {0.f, 0.f, 0.f, 0.f};

    for (int it = 0; it < 4; ++it){
        const int e0 = __builtin_amdgcn_readfirstlane((blockIdx.x*16 + g*4 + it) * 16);

        // ---- GEMM1: pre-act = emb @ W1 (K=16 zero-padded to 32) ----
        half8 ea;
        if (quad < 2){
            const float4* ep = (const float4*)(emb + (size_t)(e0+col)*16 + quad*8);
            float4 u0 = ep[0], u1 = ep[1];
            ea[0]=(_Float16)u0.x; ea[1]=(_Float16)u0.y; ea[2]=(_Float16)u0.z; ea[3]=(_Float16)u0.w;
            ea[4]=(_Float16)u1.x; ea[5]=(_Float16)u1.y; ea[6]=(_Float16)u1.z; ea[7]=(_Float16)u1.w;
        } else {
            #pragma unroll
            for (int j = 0; j < 8; ++j) ea[j] = (_Float16)0.f;
        }
        floatx4 hA = MF16(ea, fW1[0][lane], zz);
        floatx4 hB = MF16(ea, fW1[1][lane], zz);
        floatx4 hC = MF16(ea, fW1[2][lane], zz);
        floatx4 hD = MF16(ea, fW1[3][lane], zz);
        #pragma unroll
        for (int r = 0; r < 4; ++r){
            hbuf[g][quad*4+r][   col] = (_Float16)sspf(hA[r]);
            hbuf[g][quad*4+r][16+col] = (_Float16)sspf(hB[r]);
            hbuf[g][quad*4+r][32+col] = (_Float16)sspf(hC[r]);
            hbuf[g][quad*4+r][48+col] = (_Float16)sspf(hD[r]);
        }

        // ---- GEMM2: w = h @ W2 (K=64, N=128) ----
        half8 a0 = *(const half8*)&hbuf[g][col][quad*8];
        half8 a1 = *(const half8*)&hbuf[g][col][32 + quad*8];
        floatx4 wc[8];
        #pragma unroll
        for (int tile = 0; tile < 8; ++tile){
            floatx4 c = MF16(a0, fW2[tile*2+0][lane], zz);
            c = MF16(a1, fW2[tile*2+1][lane], c);
            wc[tile] = c;
        }
        #pragma unroll
        for (int tile = 0; tile < 8; ++tile){
            #pragma unroll
            for (int r = 0; r < 4; ++r)
                wbuf[g][quad*4+r][tile*16+col] = (_Float16)wc[tile][r];
        }

        // ---- uvu: km computed directly in lin A-frag layout ----
        const int em   = e0 + col;
        const int srcm = eidx[em];
        const float* fsrc = feats + (size_t)srcm*128;
        float4 yv = *(const float4*)(eattr + (size_t)em*4);
        const float y0 = yv.x, y1a = yv.y, y1b = yv.z, y1c = yv.w;

        float xs0[8];
        {
            float4 u0 = *(const float4*)(fsrc + quad*8);
            float4 u1 = *(const float4*)(fsrc + quad*8 + 4);
            xs0[0]=u0.x; xs0[1]=u0.y; xs0[2]=u0.z; xs0[3]=u0.w;
            xs0[4]=u1.x; xs0[5]=u1.y; xs0[6]=u1.z; xs0[7]=u1.w;
        }
        float x1s[24];
        #pragma unroll
        for (int q = 0; q < 6; ++q){
            float4 u = *(const float4*)(fsrc + 32 + quad*24 + q*4);
            x1s[q*4+0]=u.x; x1s[q*4+1]=u.y; x1s[q*4+2]=u.z; x1s[q*4+3]=u.w;
        }

        half8 w0h = *(const half8*)&wbuf[g][col][quad*8];
        half8 w1h = *(const half8*)&wbuf[g][col][32 + quad*8];
        half8 w2h = *(const half8*)&wbuf[g][col][64 + quad*8];
        half8 w3h = *(const half8*)&wbuf[g][col][96 + quad*8];

        half8 fk0s0, fk0s1, fc0s0, fc0s1, fc1s0, fc1s1, fc2s0, fc2s1;
        #pragma unroll
        for (int j = 0; j < 8; ++j){
            float ww0=(float)w0h[j], ww1=(float)w1h[j];
            float ww2=(float)w2h[j], ww3=(float)w3h[j];
            float x0 = xs0[j];
            float xa = x1s[3*j], xb = x1s[3*j+1], xc = x1s[3*j+2];
            fk0s0[j] = (_Float16)(ww0 * x0 * y0);
            fk0s1[j] = (_Float16)(ww3 * (xa*y1a + xb*y1b + xc*y1c) * INV_SQRT3);
            fc0s0[j] = (_Float16)(ww1 * x0 * y1a);
            fc1s0[j] = (_Float16)(ww1 * x0 * y1b);
            fc2s0[j] = (_Float16)(ww1 * x0 * y1c);
            fc0s1[j] = (_Float16)(ww2 * xa * y0);
            fc1s1[j] = (_Float16)(ww2 * xb * y0);
            fc2s1[j] = (_Float16)(ww2 * xc * y0);
        }

        // ---- lin: k = km @ WL (N=32, K=64); WL1 frags reused for 3 c ----
        floatx4 k0a = MF16(fk0s0, fL0[0][lane], zz); k0a = MF16(fk0s1, fL0[1][lane], k0a);
        floatx4 k0b = MF16(fk0s0, fL0[2][lane], zz); k0b = MF16(fk0s1, fL0[3][lane], k0b);
        floatx4 kc0a = MF16(fc0s0, fL1[0][lane], zz); kc0a = MF16(fc0s1, fL1[1][lane], kc0a);
        floatx4 kc0b = MF16(fc0s0, fL1[2][lane], zz); kc0b = MF16(fc0s1, fL1[3][lane], kc0b);
        floatx4 kc1a = MF16(fc1s0, fL1[0][lane], zz); kc1a = MF16(fc1s1, fL1[1][lane], kc1a);
        floatx4 kc1b = MF16(fc1s0, fL1[2][lane], zz); kc1b = MF16(fc1s1, fL1[3][lane], kc1b);
        floatx4 kc2a = MF16(fc2s0, fL1[0][lane], zz); kc2a = MF16(fc2s1, fL1[1][lane], kc2a);
        floatx4 kc2b = MF16(fc2s0, fL1[2][lane], zz); kc2b = MF16(fc2s1, fL1[3][lane], kc2b);

        if (PASS == 1){
            // ---- d = k . qd[dst] (scales folded in qd); 16-lane reduce ----
            #pragma unroll
            for (int r = 0; r < 4; ++r){
                int er = e0 + quad*4 + r;
                int dr = eidx[N_EDGES + er];
                const float* qdp = qdbuf + (size_t)dr*128;
                float dd = k0a[r]*qdp[col] + k0b[r]*qdp[col+16]
                    + kc0a[r]*qdp[32+3*col+0] + kc1a[r]*qdp[32+3*col+1] + kc2a[r]*qdp[32+3*col+2]
                    + kc0b[r]*qdp[32+3*(col+16)+0] + kc1b[r]*qdp[32+3*(col+16)+1] + kc2b[r]*qdp[32+3*(col+16)+2];
                dd += __shfl_xor(dd, 1);
                dd += __shfl_xor(dd, 2);
                dd += __shfl_xor(dd, 4);
                dd += __shfl_xor(dd, 8);
                if (col == 0){
                    // cutoff const: diff = pos[src]-pos[src] == 0 (reference bug)
                    float ev = 0.9048374180359595f * expf(dd);
                    expv_buf[er] = ev;
                    atomicAdd(&zbuf[dr], ev);
                }
            }
        } else {
            // ---- epilogue: coef = sqrt(relu(alpha)); atomic scatter-add ----
            #pragma unroll
            for (int r = 0; r < 4; ++r){
                int er = e0 + quad*4 + r;
                int dr = eidx[N_EDGES + er];
                float ev = expv_buf[er];
                float z  = zbuf[dr];
                z = (z == 0.f) ? 1.f : z;
                float coef = sqrtf(fmaxf(ev/z, 0.f));
                float* op = out + (size_t)dr*128;
                atomicAdd(op + col,      coef*k0a[r]);
                atomicAdd(op + col + 16, coef*k0b[r]);
                atomicAdd(op + 32+3*col+0, coef*kc0a[r]);
                atomicAdd(op + 32+3*col+1, coef*kc1a[r]);
                atomicAdd(op + 32+3*col+2, coef*kc2a[r]);
                atomicAdd(op + 32+3*(col+16)+0, coef*kc0b[r]);
                atomicAdd(op + 32+3*(col+16)+1, coef*kc1b[r]);
                atomicAdd(op + 32+3*(col+16)+2, coef*kc2b[r]);
            }
        }
    }
}

extern "C" void kernel_launch(void* const* d_in, const int* in_sizes, int n_in,
                              void* d_out, int out_size, void* d_ws, size_t ws_size,
                              hipStream_t stream)
{
    const float* feats = (const float*)d_in[0];
    const float* attrs = (const float*)d_in[1];
    const float* emb   = (const float*)d_in[2];
    const float* eattr = (const float*)d_in[3];
    // d_in[4] positions: unused (reference computes positions[src]-positions[src] == 0)
    const float* Wq0  = (const float*)d_in[5];
    const float* Wq1  = (const float*)d_in[6];
    const float* Wk1  = (const float*)d_in[7];
    const float* Wk2  = (const float*)d_in[8];
    const float* Wv1  = (const float*)d_in[9];
    const float* Wv2  = (const float*)d_in[10];
    const float* Wlk0 = (const float*)d_in[11];
    const float* Wlk1 = (const float*)d_in[12];
    const float* Wlv0 = (const float*)d_in[13];
    const float* Wlv1 = (const float*)d_in[14];
    const float* Wd0  = (const float*)d_in[15];
    const float* Wd1  = (const float*)d_in[16];
    const float* Ws0  = (const float*)d_in[17];
    const float* Ws1  = (const float*)d_in[18];
    const int*   eidx = (const int*)d_in[19];

    float* out   = (float*)d_out;
    float* qdbuf = (float*)d_ws;                  // N*128 floats (qd = Wd^T q, scaled)
    float* expv  = qdbuf + (size_t)N_NODES*128;   // E floats
    float* zbuf  = expv + (size_t)N_EDGES;        // N floats

    hipMemsetAsync(zbuf, 0, N_NODES*sizeof(float), stream);
    node_kernel<<<N_NODES, 128, 0, stream>>>(feats, attrs, Wq0, Wq1, Wd0, Wd1,
                                             Ws0, Ws1, qdbuf, out);
    edge_mfma<1><<<N_EDGES/256, 256, 0, stream>>>(feats, emb, eattr, eidx,
                                                  Wk1, Wk2, Wlk0, Wlk1,
                                                  qdbuf, expv, zbuf, out);
    edge_mfma<2><<<N_EDGES/256, 256, 0, stream>>>(feats, emb, eattr, eidx,
                                                  Wv1, Wv2, Wlv0, Wlv1,
                                                  qdbuf, expv, zbuf, out);
}

// Round 8
// 601.769 us; speedup vs baseline: 4.8573x; 1.0088x over previous
//
#include <hip/hip_runtime.h>
#include <math.h>

#define N_NODES 8192
#define N_EDGES 262144
#define INV_SQRT3 0.5773502691896258f

typedef __attribute__((ext_vector_type(8))) _Float16 half8;
typedef __attribute__((ext_vector_type(4))) float floatx4;

#define MF16(a,b,c) __builtin_amdgcn_mfma_f32_16x16x32_f16(a,b,c,0,0,0)

__device__ __forceinline__ float sspf(float x){
    // softplus(x) - ln(2), numerically stable
    float sp = (x > 20.0f) ? x : log1pf(expf(x));
    return sp - 0.6931471805599453f;
}

// ---------------------------------------------------------------------------
// Kernel A: per-node: out = sc (self-connection);
// qd = Wd^T q, all d-stage scales folded, stored PERMUTED for the edge
// kernel's d-stage: qdbuf[n][col*8+slot], slot order =
//   {qd0[col], qd0[col+16], qd1[3c],qd1[3c+1],qd1[3c+2],
//    qd1[3(c+16)],qd1[3(c+16)+1],qd1[3(c+16)+2]}  -> 2 float4 loads per lane.
// ---------------------------------------------------------------------------
__global__ __launch_bounds__(128) void node_kernel(
    const float* __restrict__ feats, const float* __restrict__ attrs,
    const float* __restrict__ Wq0, const float* __restrict__ Wq1,
    const float* __restrict__ Wd0, const float* __restrict__ Wd1,
    const float* __restrict__ Ws0, const float* __restrict__ Ws1,
    float* __restrict__ qdbuf, float* __restrict__ out)
{
    int n = blockIdx.x; int t = threadIdx.x;
    __shared__ float sf[128];
    __shared__ float sa[16];
    __shared__ float sq[128];
    __shared__ float qsh[128];
    sf[t] = feats[n*128 + t];
    if (t < 16) sa[t] = attrs[n*16 + t];
    __syncthreads();
    const float inv_sqrt32 = 0.17677669529663687f;   // 1/sqrt(32)
    const float sc_scale   = 0.04419417382415922f;   // 1/sqrt(32*16)
    const float d_scale    = 0.022097086912079608f;  // 1/sqrt(2*32*32)
    float qv, scv;
    if (t < 32){
        int v = t;
        float acc = 0.f;
        for (int u = 0; u < 32; ++u) acc += sf[u] * Wq0[u*32 + v];
        qv = acc * inv_sqrt32;
        acc = 0.f;
        for (int u = 0; u < 32; ++u){
            float su = sf[u];
            for (int a = 0; a < 16; ++a)
                acc += su * sa[a] * Ws0[(u*16 + a)*32 + v];
        }
        scv = acc * sc_scale;
    } else {
        int k = t - 32; int v = k/3; int c = k - v*3;
        float acc = 0.f;
        for (int u = 0; u < 32; ++u) acc += sf[32 + u*3 + c] * Wq1[u*32 + v];
        qv = acc * inv_sqrt32;
        acc = 0.f;
        for (int u = 0; u < 32; ++u){
            float su = sf[32 + u*3 + c];
            for (int a = 0; a < 16; ++a)
                acc += su * sa[a] * Ws1[(u*16 + a)*32 + v];
        }
        scv = acc * sc_scale;
    }
    sq[t] = qv;
    out[n*128 + t] = scv;
    __syncthreads();

    float qd;
    if (t < 32){
        int v = t;
        float acc = 0.f;
        for (int u = 0; u < 32; ++u) acc += sq[u] * Wd0[u*32 + v];
        qd = acc * d_scale;
    } else {
        int k = t - 32; int v = k/3; int c = k - v*3;
        float acc = 0.f;
        for (int u = 0; u < 32; ++u) acc += sq[32 + u*3 + c] * Wd1[u*32 + v];
        qd = acc * d_scale * INV_SQRT3;
    }
    qsh[t] = qd;
    __syncthreads();

    // permuted store
    {
        int col = t >> 3, slot = t & 7;
        int src;
        if      (slot == 0) src = col;
        else if (slot == 1) src = col + 16;
        else if (slot <  5) src = 32 + 3*col + (slot-2);
        else                src = 32 + 3*(col+16) + (slot-5);
        qdbuf[n*128 + t] = qsh[src];
    }
}

// ---------------------------------------------------------------------------
// MERGED MFMA edge kernel: k-path -> ev (= cutoff*exp(d)), atomic z[dst];
// then v-path with coef = sqrt(ev) -> atomic acc[dst] (un-normalized msg sum).
// Uses sqrt(alpha) = sqrt(ev)/sqrt(z): z applied later in finalize.
// One wave = 16 edges/iter, 4 iters. mfma_f32_16x16x32_f16 layouts
// (measured, learn_hip m89/m120): A[m=lane&15][k=quad*8+j];
// B[k=quad*8+j][n=lane&15]; C col=lane&15, row=quad*4+reg.
// LDS: 56 weight frag tiles (57344 B, both paths, scales folded) +
// overlaid h/w staging 4x16x136 fp16 (17408 B) = 74752 B -> 2 blocks/CU.
// All unrolled arrays have compile-time indices (no scratch demotion).
// ---------------------------------------------------------------------------
__global__ __launch_bounds__(256) void edge_mfma(
    const float* __restrict__ feats, const float* __restrict__ emb,
    const float* __restrict__ eattr, const int* __restrict__ eidx,
    const float* __restrict__ W1k, const float* __restrict__ W2k,
    const float* __restrict__ WL0k, const float* __restrict__ WL1k,
    const float* __restrict__ W1v, const float* __restrict__ W2v,
    const float* __restrict__ WL0v, const float* __restrict__ WL1v,
    const float* __restrict__ qdbuf,
    float* __restrict__ zbuf, float* __restrict__ accb)
{
    __shared__ half8 fW1K[4][64];
    __shared__ half8 fW1V[4][64];
    __shared__ half8 fW2K[16][64];
    __shared__ half8 fW2V[16][64];
    __shared__ half8 fL0K[4][64];
    __shared__ half8 fL1K[4][64];
    __shared__ half8 fL0V[4][64];
    __shared__ half8 fL1V[4][64];
    __shared__ _Float16 stag[4][16][136];   // h (cols 0..63) then w (0..127)

    const int t    = threadIdx.x;
    const int lane = t & 63;
    const int col  = lane & 15;
    const int quad = lane >> 4;
    const int g    = t >> 6;

    // ---- preload weight fragments (scales folded) ----
    {
        half8 f, fv;
        #pragma unroll
        for (int j = 0; j < 8; ++j){
            int k = quad*8 + j;
            f[j]  = (k < 16) ? (_Float16)(W1k[k*64 + g*16 + col] * 0.25f) : (_Float16)0.f;
            fv[j] = (k < 16) ? (_Float16)(W1v[k*64 + g*16 + col] * 0.25f) : (_Float16)0.f;
        }
        fW1K[g][lane] = f; fW1V[g][lane] = fv;
    }
    #pragma unroll
    for (int ff = 0; ff < 4; ++ff){
        int fr = g*4 + ff, tile = fr >> 1, s = fr & 1;
        half8 f, fv;
        #pragma unroll
        for (int j = 0; j < 8; ++j){
            int k = (s*32 + quad*8 + j)*128 + tile*16 + col;
            f[j]  = (_Float16)(W2k[k] * 0.125f);
            fv[j] = (_Float16)(W2v[k] * 0.125f);
        }
        fW2K[fr][lane] = f; fW2V[fr][lane] = fv;
    }
    {
        int tile = g >> 1, s = g & 1;
        half8 f0, f1, f2, f3;
        #pragma unroll
        for (int j = 0; j < 8; ++j){
            int k = (s*32 + quad*8 + j)*32 + tile*16 + col;
            f0[j] = (_Float16)(WL0k[k] * 0.125f);
            f1[j] = (_Float16)(WL1k[k] * 0.125f);
            f2[j] = (_Float16)(WL0v[k] * 0.125f);
            f3[j] = (_Float16)(WL1v[k] * 0.125f);
        }
        fL0K[g][lane] = f0; fL1K[g][lane] = f1;
        fL0V[g][lane] = f2; fL1V[g][lane] = f3;
    }
    __syncthreads();     // the only block-wide barrier

    const floatx4 zzero = {0.f, 0.f, 0.f, 0.f};

    for (int it = 0; it < 4; ++it){
        const int e0 = __builtin_amdgcn_readfirstlane((blockIdx.x*16 + g*4 + it) * 16);

        // ---- shared A-fragment: emb rows (K=16 zero-padded to 32) ----
        half8 ea;
        if (quad < 2){
            const float4* ep = (const float4*)(emb + (size_t)(e0+col)*16 + quad*8);
            float4 u0 = ep[0], u1 = ep[1];
            ea[0]=(_Float16)u0.x; ea[1]=(_Float16)u0.y; ea[2]=(_Float16)u0.z; ea[3]=(_Float16)u0.w;
            ea[4]=(_Float16)u1.x; ea[5]=(_Float16)u1.y; ea[6]=(_Float16)u1.z; ea[7]=(_Float16)u1.w;
        } else {
            #pragma unroll
            for (int j = 0; j < 8; ++j) ea[j] = (_Float16)0.f;
        }

        // ---- shared gathers: xs (feats of src), y (eattr), dst ids ----
        const int em   = e0 + col;
        const int srcm = eidx[em];
        const float* fsrc = feats + (size_t)srcm*128;
        float4 yv = *(const float4*)(eattr + (size_t)em*4);
        const float y0 = yv.x, y1a = yv.y, y1b = yv.z, y1c = yv.w;

        float xs0[8];
        {
            float4 u0 = *(const float4*)(fsrc + quad*8);
            float4 u1 = *(const float4*)(fsrc + quad*8 + 4);
            xs0[0]=u0.x; xs0[1]=u0.y; xs0[2]=u0.z; xs0[3]=u0.w;
            xs0[4]=u1.x; xs0[5]=u1.y; xs0[6]=u1.z; xs0[7]=u1.w;
        }
        float x1s[24];
        #pragma unroll
        for (int q = 0; q < 6; ++q){
            float4 u = *(const float4*)(fsrc + 32 + quad*24 + q*4);
            x1s[q*4+0]=u.x; x1s[q*4+1]=u.y; x1s[q*4+2]=u.z; x1s[q*4+3]=u.w;
        }
        const int dr0 = eidx[N_EDGES + e0 + quad*4 + 0];
        const int dr1 = eidx[N_EDGES + e0 + quad*4 + 1];
        const int dr2 = eidx[N_EDGES + e0 + quad*4 + 2];
        const int dr3 = eidx[N_EDGES + e0 + quad*4 + 3];

        float coef0, coef1, coef2, coef3;   // sqrt(ev) per owned edge

        // ================= K-PATH =================
        {
            // GEMM1k -> ssp -> h staging
            floatx4 hA = MF16(ea, fW1K[0][lane], zzero);
            floatx4 hB = MF16(ea, fW1K[1][lane], zzero);
            floatx4 hC = MF16(ea, fW1K[2][lane], zzero);
            floatx4 hD = MF16(ea, fW1K[3][lane], zzero);
            #pragma unroll
            for (int r = 0; r < 4; ++r){
                stag[g][quad*4+r][   col] = (_Float16)sspf(hA[r]);
                stag[g][quad*4+r][16+col] = (_Float16)sspf(hB[r]);
                stag[g][quad*4+r][32+col] = (_Float16)sspf(hC[r]);
                stag[g][quad*4+r][48+col] = (_Float16)sspf(hD[r]);
            }
            half8 a0 = *(const half8*)&stag[g][col][quad*8];
            half8 a1 = *(const half8*)&stag[g][col][32 + quad*8];
            // GEMM2k: w = h @ W2 (writes overlay h; same-wave DS in-order)
            floatx4 wc0 = MF16(a0, fW2K[ 0][lane], zzero); wc0 = MF16(a1, fW2K[ 1][lane], wc0);
            floatx4 wc1 = MF16(a0, fW2K[ 2][lane], zzero); wc1 = MF16(a1, fW2K[ 3][lane], wc1);
            floatx4 wc2 = MF16(a0, fW2K[ 4][lane], zzero); wc2 = MF16(a1, fW2K[ 5][lane], wc2);
            floatx4 wc3 = MF16(a0, fW2K[ 6][lane], zzero); wc3 = MF16(a1, fW2K[ 7][lane], wc3);
            floatx4 wc4 = MF16(a0, fW2K[ 8][lane], zzero); wc4 = MF16(a1, fW2K[ 9][lane], wc4);
            floatx4 wc5 = MF16(a0, fW2K[10][lane], zzero); wc5 = MF16(a1, fW2K[11][lane], wc5);
            floatx4 wc6 = MF16(a0, fW2K[12][lane], zzero); wc6 = MF16(a1, fW2K[13][lane], wc6);
            floatx4 wc7 = MF16(a0, fW2K[14][lane], zzero); wc7 = MF16(a1, fW2K[15][lane], wc7);
            #pragma unroll
            for (int r = 0; r < 4; ++r){
                stag[g][quad*4+r][  0+col] = (_Float16)wc0[r];
                stag[g][quad*4+r][ 16+col] = (_Float16)wc1[r];
                stag[g][quad*4+r][ 32+col] = (_Float16)wc2[r];
                stag[g][quad*4+r][ 48+col] = (_Float16)wc3[r];
                stag[g][quad*4+r][ 64+col] = (_Float16)wc4[r];
                stag[g][quad*4+r][ 80+col] = (_Float16)wc5[r];
                stag[g][quad*4+r][ 96+col] = (_Float16)wc6[r];
                stag[g][quad*4+r][112+col] = (_Float16)wc7[r];
            }
            half8 w0h = *(const half8*)&stag[g][col][     quad*8];
            half8 w1h = *(const half8*)&stag[g][col][32 + quad*8];
            half8 w2h = *(const half8*)&stag[g][col][64 + quad*8];
            half8 w3h = *(const half8*)&stag[g][col][96 + quad*8];

            half8 fk0s0, fk0s1, fc0s0, fc0s1, fc1s0, fc1s1, fc2s0, fc2s1;
            #pragma unroll
            for (int j = 0; j < 8; ++j){
                float ww0=(float)w0h[j], ww1=(float)w1h[j];
                float ww2=(float)w2h[j], ww3=(float)w3h[j];
                float x0 = xs0[j];
                float xa = x1s[3*j], xb = x1s[3*j+1], xc = x1s[3*j+2];
                fk0s0[j] = (_Float16)(ww0 * x0 * y0);
                fk0s1[j] = (_Float16)(ww3 * (xa*y1a + xb*y1b + xc*y1c) * INV_SQRT3);
                fc0s0[j] = (_Float16)(ww1 * x0 * y1a);
                fc1s0[j] = (_Float16)(ww1 * x0 * y1b);
                fc2s0[j] = (_Float16)(ww1 * x0 * y1c);
                fc0s1[j] = (_Float16)(ww2 * xa * y0);
                fc1s1[j] = (_Float16)(ww2 * xb * y0);
                fc2s1[j] = (_Float16)(ww2 * xc * y0);
            }
            floatx4 k0a = MF16(fk0s0, fL0K[0][lane], zzero); k0a = MF16(fk0s1, fL0K[1][lane], k0a);
            floatx4 k0b = MF16(fk0s0, fL0K[2][lane], zzero); k0b = MF16(fk0s1, fL0K[3][lane], k0b);
            floatx4 kc0a = MF16(fc0s0, fL1K[0][lane], zzero); kc0a = MF16(fc0s1, fL1K[1][lane], kc0a);
            floatx4 kc0b = MF16(fc0s0, fL1K[2][lane], zzero); kc0b = MF16(fc0s1, fL1K[3][lane], kc0b);
            floatx4 kc1a = MF16(fc1s0, fL1K[0][lane], zzero); kc1a = MF16(fc1s1, fL1K[1][lane], kc1a);
            floatx4 kc1b = MF16(fc1s0, fL1K[2][lane], zzero); kc1b = MF16(fc1s1, fL1K[3][lane], kc1b);
            floatx4 kc2a = MF16(fc2s0, fL1K[0][lane], zzero); kc2a = MF16(fc2s1, fL1K[1][lane], kc2a);
            floatx4 kc2b = MF16(fc2s0, fL1K[2][lane], zzero); kc2b = MF16(fc2s1, fL1K[3][lane], kc2b);

            // d-stage: permuted qd -> 2 float4 gathers per (lane,r)
            #pragma unroll
            for (int r = 0; r < 4; ++r){
                int dr = (r==0)?dr0:(r==1)?dr1:(r==2)?dr2:dr3;
                const float* qdp = qdbuf + (size_t)dr*128 + col*8;
                float4 qa = *(const float4*)qdp;
                float4 qb = *(const float4*)(qdp+4);
                float k0ar=k0a[r], k0br=k0b[r], c0ar=kc0a[r], c1ar=kc1a[r],
                      c2ar=kc2a[r], c0br=kc0b[r], c1br=kc1b[r], c2br=kc2b[r];
                float dd = k0ar*qa.x + k0br*qa.y + c0ar*qa.z + c1ar*qa.w
                         + c2ar*qb.x + c0br*qb.y + c1br*qb.z + c2br*qb.w;
                dd += __shfl_xor(dd, 1);
                dd += __shfl_xor(dd, 2);
                dd += __shfl_xor(dd, 4);
                dd += __shfl_xor(dd, 8);
                // cutoff const: diff = pos[src]-pos[src] == 0 (reference bug)
                float ev = 0.9048374180359595f * expf(dd);
                if (col == 0) atomicAdd(&zbuf[dr], ev);
                float cf = sqrtf(ev);
                if (r==0) coef0 = cf; else if (r==1) coef1 = cf;
                else if (r==2) coef2 = cf; else coef3 = cf;
            }
        }

        // ================= V-PATH (reuses ea, xs, y) =================
        {
            floatx4 hA = MF16(ea, fW1V[0][lane], zzero);
            floatx4 hB = MF16(ea, fW1V[1][lane], zzero);
            floatx4 hC = MF16(ea, fW1V[2][lane], zzero);
            floatx4 hD = MF16(ea, fW1V[3][lane], zzero);
            #pragma unroll
            for (int r = 0; r < 4; ++r){
                stag[g][quad*4+r][   col] = (_Float16)sspf(hA[r]);
                stag[g][quad*4+r][16+col] = (_Float16)sspf(hB[r]);
                stag[g][quad*4+r][32+col] = (_Float16)sspf(hC[r]);
                stag[g][quad*4+r][48+col] = (_Float16)sspf(hD[r]);
            }
            half8 a0 = *(const half8*)&stag[g][col][quad*8];
            half8 a1 = *(const half8*)&stag[g][col][32 + quad*8];
            floatx4 wc0 = MF16(a0, fW2V[ 0][lane], zzero); wc0 = MF16(a1, fW2V[ 1][lane], wc0);
            floatx4 wc1 = MF16(a0, fW2V[ 2][lane], zzero); wc1 = MF16(a1, fW2V[ 3][lane], wc1);
            floatx4 wc2 = MF16(a0, fW2V[ 4][lane], zzero); wc2 = MF16(a1, fW2V[ 5][lane], wc2);
            floatx4 wc3 = MF16(a0, fW2V[ 6][lane], zzero); wc3 = MF16(a1, fW2V[ 7][lane], wc3);
            floatx4 wc4 = MF16(a0, fW2V[ 8][lane], zzero); wc4 = MF16(a1, fW2V[ 9][lane], wc4);
            floatx4 wc5 = MF16(a0, fW2V[10][lane], zzero); wc5 = MF16(a1, fW2V[11][lane], wc5);
            floatx4 wc6 = MF16(a0, fW2V[12][lane], zzero); wc6 = MF16(a1, fW2V[13][lane], wc6);
            floatx4 wc7 = MF16(a0, fW2V[14][lane], zzero); wc7 = MF16(a1, fW2V[15][lane], wc7);
            #pragma unroll
            for (int r = 0; r < 4; ++r){
                stag[g][quad*4+r][  0+col] = (_Float16)wc0[r];
                stag[g][quad*4+r][ 16+col] = (_Float16)wc1[r];
                stag[g][quad*4+r][ 32+col] = (_Float16)wc2[r];
                stag[g][quad*4+r][ 48+col] = (_Float16)wc3[r];
                stag[g][quad*4+r][ 64+col] = (_Float16)wc4[r];
                stag[g][quad*4+r][ 80+col] = (_Float16)wc5[r];
                stag[g][quad*4+r][ 96+col] = (_Float16)wc6[r];
                stag[g][quad*4+r][112+col] = (_Float16)wc7[r];
            }
            half8 w0h = *(const half8*)&stag[g][col][     quad*8];
            half8 w1h = *(const half8*)&stag[g][col][32 + quad*8];
            half8 w2h = *(const half8*)&stag[g][col][64 + quad*8];
            half8 w3h = *(const half8*)&stag[g][col][96 + quad*8];

            half8 fk0s0, fk0s1, fc0s0, fc0s1, fc1s0, fc1s1, fc2s0, fc2s1;
            #pragma unroll
            for (int j = 0; j < 8; ++j){
                float ww0=(float)w0h[j], ww1=(float)w1h[j];
                float ww2=(float)w2h[j], ww3=(float)w3h[j];
                float x0 = xs0[j];
                float xa = x1s[3*j], xb = x1s[3*j+1], xc = x1s[3*j+2];
                fk0s0[j] = (_Float16)(ww0 * x0 * y0);
                fk0s1[j] = (_Float16)(ww3 * (xa*y1a + xb*y1b + xc*y1c) * INV_SQRT3);
                fc0s0[j] = (_Float16)(ww1 * x0 * y1a);
                fc1s0[j] = (_Float16)(ww1 * x0 * y1b);
                fc2s0[j] = (_Float16)(ww1 * x0 * y1c);
                fc0s1[j] = (_Float16)(ww2 * xa * y0);
                fc1s1[j] = (_Float16)(ww2 * xb * y0);
                fc2s1[j] = (_Float16)(ww2 * xc * y0);
            }
            floatx4 k0a = MF16(fk0s0, fL0V[0][lane], zzero); k0a = MF16(fk0s1, fL0V[1][lane], k0a);
            floatx4 k0b = MF16(fk0s0, fL0V[2][lane], zzero); k0b = MF16(fk0s1, fL0V[3][lane], k0b);
            floatx4 kc0a = MF16(fc0s0, fL1V[0][lane], zzero); kc0a = MF16(fc0s1, fL1V[1][lane], kc0a);
            floatx4 kc0b = MF16(fc0s0, fL1V[2][lane], zzero); kc0b = MF16(fc0s1, fL1V[3][lane], kc0b);
            floatx4 kc1a = MF16(fc1s0, fL1V[0][lane], zzero); kc1a = MF16(fc1s1, fL1V[1][lane], kc1a);
            floatx4 kc1b = MF16(fc1s0, fL1V[2][lane], zzero); kc1b = MF16(fc1s1, fL1V[3][lane], kc1b);
            floatx4 kc2a = MF16(fc2s0, fL1V[0][lane], zzero); kc2a = MF16(fc2s1, fL1V[1][lane], kc2a);
            floatx4 kc2b = MF16(fc2s0, fL1V[2][lane], zzero); kc2b = MF16(fc2s1, fL1V[3][lane], kc2b);

            // epilogue: acc[dst] += sqrt(ev) * v (z applied in finalize)
            #pragma unroll
            for (int r = 0; r < 4; ++r){
                int dr    = (r==0)?dr0:(r==1)?dr1:(r==2)?dr2:dr3;
                float cf  = (r==0)?coef0:(r==1)?coef1:(r==2)?coef2:coef3;
                float* op = accb + (size_t)dr*128;
                atomicAdd(op + col,      cf*k0a[r]);
                atomicAdd(op + col + 16, cf*k0b[r]);
                atomicAdd(op + 32+3*col+0, cf*kc0a[r]);
                atomicAdd(op + 32+3*col+1, cf*kc1a[r]);
                atomicAdd(op + 32+3*col+2, cf*kc2a[r]);
                atomicAdd(op + 32+3*(col+16)+0, cf*kc0b[r]);
                atomicAdd(op + 32+3*(col+16)+1, cf*kc1b[r]);
                atomicAdd(op + 32+3*(col+16)+2, cf*kc2b[r]);
            }
        }
    }
}

// ---------------------------------------------------------------------------
// Finalize: out = sc + acc / sqrt(z)   (z==0 -> no incoming edges -> acc==0)
// ---------------------------------------------------------------------------
__global__ __launch_bounds__(256) void finalize_kernel(
    const float* __restrict__ accb, const float* __restrict__ zbuf,
    float* __restrict__ out)
{
    int idx = blockIdx.x*256 + threadIdx.x;
    int n = idx >> 7;
    float z = zbuf[n];
    float f = (z > 0.f) ? rsqrtf(z) : 0.f;
    out[idx] += accb[idx] * f;
}

extern "C" void kernel_launch(void* const* d_in, const int* in_sizes, int n_in,
                              void* d_out, int out_size, void* d_ws, size_t ws_size,
                              hipStream_t stream)
{
    const float* feats = (const float*)d_in[0];
    const float* attrs = (const float*)d_in[1];
    const float* emb   = (const float*)d_in[2];
    const float* eattr = (const float*)d_in[3];
    // d_in[4] positions: unused (reference computes positions[src]-positions[src] == 0)
    const float* Wq0  = (const float*)d_in[5];
    const float* Wq1  = (const float*)d_in[6];
    const float* Wk1  = (const float*)d_in[7];
    const float* Wk2  = (const float*)d_in[8];
    const float* Wv1  = (const float*)d_in[9];
    const float* Wv2  = (const float*)d_in[10];
    const float* Wlk0 = (const float*)d_in[11];
    const float* Wlk1 = (const float*)d_in[12];
    const float* Wlv0 = (const float*)d_in[13];
    const float* Wlv1 = (const float*)d_in[14];
    const float* Wd0  = (const float*)d_in[15];
    const float* Wd1  = (const float*)d_in[16];
    const float* Ws0  = (const float*)d_in[17];
    const float* Ws1  = (const float*)d_in[18];
    const int*   eidx = (const int*)d_in[19];

    float* out   = (float*)d_out;
    float* qdbuf = (float*)d_ws;                    // N*128 (permuted qd)
    float* zbuf  = qdbuf + (size_t)N_NODES*128;     // N
    float* accb  = zbuf  + (size_t)N_NODES;         // N*128

    hipMemsetAsync(zbuf, 0, (N_NODES + N_NODES*128)*sizeof(float), stream);
    node_kernel<<<N_NODES, 128, 0, stream>>>(feats, attrs, Wq0, Wq1, Wd0, Wd1,
                                             Ws0, Ws1, qdbuf, out);
    edge_mfma<<<N_EDGES/256, 256, 0, stream>>>(feats, emb, eattr, eidx,
                                               Wk1, Wk2, Wlk0, Wlk1,
                                               Wv1, Wv2, Wlv0, Wlv1,
                                               qdbuf, zbuf, accb);
    finalize_kernel<<<N_NODES*128/256, 256, 0, stream>>>(accb, zbuf, out);
}

// Round 9
// 587.145 us; speedup vs baseline: 4.9783x; 1.0249x over previous
//
#include <hip/hip_runtime.h>
#include <math.h>

#define N_NODES 8192
#define N_EDGES 262144
#define INV_SQRT3 0.5773502691896258f

typedef __attribute__((ext_vector_type(8))) _Float16 half8;
typedef __attribute__((ext_vector_type(4))) float floatx4;

#define MF16(a,b,c) __builtin_amdgcn_mfma_f32_16x16x32_f16(a,b,c,0,0,0)

__device__ __forceinline__ float sspf(float x){
    // softplus(x) - ln(2), numerically stable
    float sp = (x > 20.0f) ? x : log1pf(expf(x));
    return sp - 0.6931471805599453f;
}

// ---------------------------------------------------------------------------
// Kernel A: per-node: out = sc (self-connection);
// qd = Wd^T q, all d-stage scales folded, stored PERMUTED:
// qdbuf[n][col*8+slot], slot = {qd0[c], qd0[c+16], qd1[3c..3c+2],
// qd1[3(c+16)..+2]} -> 2 float4 loads per lane in the edge kernel.
// ---------------------------------------------------------------------------
__global__ __launch_bounds__(128) void node_kernel(
    const float* __restrict__ feats, const float* __restrict__ attrs,
    const float* __restrict__ Wq0, const float* __restrict__ Wq1,
    const float* __restrict__ Wd0, const float* __restrict__ Wd1,
    const float* __restrict__ Ws0, const float* __restrict__ Ws1,
    float* __restrict__ qdbuf, float* __restrict__ out)
{
    int n = blockIdx.x; int t = threadIdx.x;
    __shared__ float sf[128];
    __shared__ float sa[16];
    __shared__ float sq[128];
    __shared__ float qsh[128];
    sf[t] = feats[n*128 + t];
    if (t < 16) sa[t] = attrs[n*16 + t];
    __syncthreads();
    const float inv_sqrt32 = 0.17677669529663687f;   // 1/sqrt(32)
    const float sc_scale   = 0.04419417382415922f;   // 1/sqrt(32*16)
    const float d_scale    = 0.022097086912079608f;  // 1/sqrt(2*32*32)
    float qv, scv;
    if (t < 32){
        int v = t;
        float acc = 0.f;
        for (int u = 0; u < 32; ++u) acc += sf[u] * Wq0[u*32 + v];
        qv = acc * inv_sqrt32;
        acc = 0.f;
        for (int u = 0; u < 32; ++u){
            float su = sf[u];
            for (int a = 0; a < 16; ++a)
                acc += su * sa[a] * Ws0[(u*16 + a)*32 + v];
        }
        scv = acc * sc_scale;
    } else {
        int k = t - 32; int v = k/3; int c = k - v*3;
        float acc = 0.f;
        for (int u = 0; u < 32; ++u) acc += sf[32 + u*3 + c] * Wq1[u*32 + v];
        qv = acc * inv_sqrt32;
        acc = 0.f;
        for (int u = 0; u < 32; ++u){
            float su = sf[32 + u*3 + c];
            for (int a = 0; a < 16; ++a)
                acc += su * sa[a] * Ws1[(u*16 + a)*32 + v];
        }
        scv = acc * sc_scale;
    }
    sq[t] = qv;
    out[n*128 + t] = scv;
    __syncthreads();

    float qd;
    if (t < 32){
        int v = t;
        float acc = 0.f;
        for (int u = 0; u < 32; ++u) acc += sq[u] * Wd0[u*32 + v];
        qd = acc * d_scale;
    } else {
        int k = t - 32; int v = k/3; int c = k - v*3;
        float acc = 0.f;
        for (int u = 0; u < 32; ++u) acc += sq[32 + u*3 + c] * Wd1[u*32 + v];
        qd = acc * d_scale * INV_SQRT3;
    }
    qsh[t] = qd;
    __syncthreads();
    {
        int col = t >> 3, slot = t & 7;
        int src;
        if      (slot == 0) src = col;
        else if (slot == 1) src = col + 16;
        else if (slot <  5) src = 32 + 3*col + (slot-2);
        else                src = 32 + 3*(col+16) + (slot-5);
        qdbuf[n*128 + t] = qsh[src];
    }
}

// ---------------------------------------------------------------------------
// CSR build: histogram by dst -> exclusive scan -> scatter permutation.
// ---------------------------------------------------------------------------
__global__ __launch_bounds__(256) void count_kernel(
    const int* __restrict__ eidx, int* __restrict__ degb)
{
    int e = blockIdx.x*256 + threadIdx.x;
    atomicAdd(&degb[eidx[N_EDGES + e]], 1);
}

__global__ __launch_bounds__(256) void scan_kernel(
    const int* __restrict__ degb, int* __restrict__ rowstart,
    int* __restrict__ cursor)
{
    __shared__ int part[256];
    int t = threadIdx.x;
    int loc[32];
    int s = 0;
    #pragma unroll
    for (int i = 0; i < 32; ++i){ loc[i] = s; s += degb[t*32 + i]; }
    part[t] = s;
    __syncthreads();
    for (int d = 1; d < 256; d <<= 1){
        int v = (t >= d) ? part[t-d] : 0;
        __syncthreads();
        part[t] += v;
        __syncthreads();
    }
    int excl = part[t] - s;
    #pragma unroll
    for (int i = 0; i < 32; ++i){
        int v = excl + loc[i];
        rowstart[t*32 + i] = v;
        cursor[t*32 + i]   = v;
    }
    if (t == 255) rowstart[N_NODES] = excl + s;
}

__global__ __launch_bounds__(256) void scatter_kernel(
    const int* __restrict__ eidx, int* __restrict__ cursor,
    int* __restrict__ perm)
{
    int e = blockIdx.x*256 + threadIdx.x;
    int p = atomicAdd(&cursor[eidx[N_EDGES + e]], 1);
    perm[p] = e;
}

// ---------------------------------------------------------------------------
// Node-centric MFMA edge kernel: one wave per dst node; its in-edges
// (CSR perm) processed in M=16 tiles. Per tile: shared A-frags (emb/xs/y),
// K-path -> dd -> ev (masked for tail), V-path -> register accumulation
// macc += sqrt(ev)*v; z accumulated in registers. End: out[n] += macc*rsqrt(z)
// via plain stores. NO GLOBAL ATOMICS in this kernel.
// mfma_f32_16x16x32_f16 layouts (measured, learn_hip m89/m120):
// A[m=lane&15][k=quad*8+j]; B[k=quad*8+j][n=lane&15]; C col=lane&15,
// row=quad*4+reg. LDS: 56 KB weight frags (both paths, scales folded) +
// 17 KB h/w staging = 74752 B -> 2 blocks/CU.
// ---------------------------------------------------------------------------
__global__ __launch_bounds__(256) void edge_mfma(
    const float* __restrict__ feats, const float* __restrict__ emb,
    const float* __restrict__ eattr, const int* __restrict__ eidx,
    const float* __restrict__ W1k, const float* __restrict__ W2k,
    const float* __restrict__ WL0k, const float* __restrict__ WL1k,
    const float* __restrict__ W1v, const float* __restrict__ W2v,
    const float* __restrict__ WL0v, const float* __restrict__ WL1v,
    const float* __restrict__ qdbuf,
    const int* __restrict__ rowstart, const int* __restrict__ perm,
    float* __restrict__ out)
{
    __shared__ half8 fW1K[4][64];
    __shared__ half8 fW1V[4][64];
    __shared__ half8 fW2K[16][64];
    __shared__ half8 fW2V[16][64];
    __shared__ half8 fL0K[4][64];
    __shared__ half8 fL1K[4][64];
    __shared__ half8 fL0V[4][64];
    __shared__ half8 fL1V[4][64];
    __shared__ _Float16 stag[4][16][136];

    const int t    = threadIdx.x;
    const int lane = t & 63;
    const int col  = lane & 15;
    const int quad = lane >> 4;
    const int g    = t >> 6;

    // ---- preload weight fragments (scales folded) ----
    {
        half8 f, fv;
        #pragma unroll
        for (int j = 0; j < 8; ++j){
            int k = quad*8 + j;
            f[j]  = (k < 16) ? (_Float16)(W1k[k*64 + g*16 + col] * 0.25f) : (_Float16)0.f;
            fv[j] = (k < 16) ? (_Float16)(W1v[k*64 + g*16 + col] * 0.25f) : (_Float16)0.f;
        }
        fW1K[g][lane] = f; fW1V[g][lane] = fv;
    }
    #pragma unroll
    for (int ff = 0; ff < 4; ++ff){
        int fr = g*4 + ff, tile = fr >> 1, s = fr & 1;
        half8 f, fv;
        #pragma unroll
        for (int j = 0; j < 8; ++j){
            int k = (s*32 + quad*8 + j)*128 + tile*16 + col;
            f[j]  = (_Float16)(W2k[k] * 0.125f);
            fv[j] = (_Float16)(W2v[k] * 0.125f);
        }
        fW2K[fr][lane] = f; fW2V[fr][lane] = fv;
    }
    {
        int tile = g >> 1, s = g & 1;
        half8 f0, f1, f2, f3;
        #pragma unroll
        for (int j = 0; j < 8; ++j){
            int k = (s*32 + quad*8 + j)*32 + tile*16 + col;
            f0[j] = (_Float16)(WL0k[k] * 0.125f);
            f1[j] = (_Float16)(WL1k[k] * 0.125f);
            f2[j] = (_Float16)(WL0v[k] * 0.125f);
            f3[j] = (_Float16)(WL1v[k] * 0.125f);
        }
        fL0K[g][lane] = f0; fL1K[g][lane] = f1;
        fL0V[g][lane] = f2; fL1V[g][lane] = f3;
    }
    __syncthreads();     // the only block-wide barrier

    const floatx4 zzero = {0.f, 0.f, 0.f, 0.f};

    const int n  = blockIdx.x*4 + g;
    const int r0 = rowstart[n];
    const int dcount = rowstart[n+1] - r0;

    // hoisted per-node qd (permuted layout -> 2 float4 per lane)
    const float* qdp = qdbuf + (size_t)n*128 + col*8;
    const float4 qa = *(const float4*)qdp;
    const float4 qb = *(const float4*)(qdp + 4);

    // per-lane accumulators (named scalars; never indexable)
    float macc0=0.f, macc1=0.f, macc2=0.f, macc3=0.f;
    float macc4=0.f, macc5=0.f, macc6=0.f, macc7=0.f;
    float zacc = 0.f;

    for (int tb = 0; tb < dcount; tb += 16){
        // edge for this lane's A-column (clamped; tail rows masked at ev)
        int slot = tb + col;
        int eA = perm[r0 + ((slot < dcount) ? slot : (dcount-1))];

        // ---- shared A-fragment: emb rows (K=16 zero-padded to 32) ----
        half8 ea;
        if (quad < 2){
            const float4* ep = (const float4*)(emb + (size_t)eA*16 + quad*8);
            float4 u0 = ep[0], u1 = ep[1];
            ea[0]=(_Float16)u0.x; ea[1]=(_Float16)u0.y; ea[2]=(_Float16)u0.z; ea[3]=(_Float16)u0.w;
            ea[4]=(_Float16)u1.x; ea[5]=(_Float16)u1.y; ea[6]=(_Float16)u1.z; ea[7]=(_Float16)u1.w;
        } else {
            #pragma unroll
            for (int j = 0; j < 8; ++j) ea[j] = (_Float16)0.f;
        }

        const int srcm = eidx[eA];
        const float* fsrc = feats + (size_t)srcm*128;
        float4 yv = *(const float4*)(eattr + (size_t)eA*4);
        const float y0 = yv.x, y1a = yv.y, y1b = yv.z, y1c = yv.w;

        float xs0[8];
        {
            float4 u0 = *(const float4*)(fsrc + quad*8);
            float4 u1 = *(const float4*)(fsrc + quad*8 + 4);
            xs0[0]=u0.x; xs0[1]=u0.y; xs0[2]=u0.z; xs0[3]=u0.w;
            xs0[4]=u1.x; xs0[5]=u1.y; xs0[6]=u1.z; xs0[7]=u1.w;
        }
        float x1s[24];
        #pragma unroll
        for (int q = 0; q < 6; ++q){
            float4 u = *(const float4*)(fsrc + 32 + quad*24 + q*4);
            x1s[q*4+0]=u.x; x1s[q*4+1]=u.y; x1s[q*4+2]=u.z; x1s[q*4+3]=u.w;
        }

        float coef0, coef1, coef2, coef3;   // sqrt(ev) per owned edge row

        // ================= K-PATH =================
        {
            floatx4 hA = MF16(ea, fW1K[0][lane], zzero);
            floatx4 hB = MF16(ea, fW1K[1][lane], zzero);
            floatx4 hC = MF16(ea, fW1K[2][lane], zzero);
            floatx4 hD = MF16(ea, fW1K[3][lane], zzero);
            #pragma unroll
            for (int r = 0; r < 4; ++r){
                stag[g][quad*4+r][   col] = (_Float16)sspf(hA[r]);
                stag[g][quad*4+r][16+col] = (_Float16)sspf(hB[r]);
                stag[g][quad*4+r][32+col] = (_Float16)sspf(hC[r]);
                stag[g][quad*4+r][48+col] = (_Float16)sspf(hD[r]);
            }
            half8 a0 = *(const half8*)&stag[g][col][quad*8];
            half8 a1 = *(const half8*)&stag[g][col][32 + quad*8];
            floatx4 wc0 = MF16(a0, fW2K[ 0][lane], zzero); wc0 = MF16(a1, fW2K[ 1][lane], wc0);
            floatx4 wc1 = MF16(a0, fW2K[ 2][lane], zzero); wc1 = MF16(a1, fW2K[ 3][lane], wc1);
            floatx4 wc2 = MF16(a0, fW2K[ 4][lane], zzero); wc2 = MF16(a1, fW2K[ 5][lane], wc2);
            floatx4 wc3 = MF16(a0, fW2K[ 6][lane], zzero); wc3 = MF16(a1, fW2K[ 7][lane], wc3);
            floatx4 wc4 = MF16(a0, fW2K[ 8][lane], zzero); wc4 = MF16(a1, fW2K[ 9][lane], wc4);
            floatx4 wc5 = MF16(a0, fW2K[10][lane], zzero); wc5 = MF16(a1, fW2K[11][lane], wc5);
            floatx4 wc6 = MF16(a0, fW2K[12][lane], zzero); wc6 = MF16(a1, fW2K[13][lane], wc6);
            floatx4 wc7 = MF16(a0, fW2K[14][lane], zzero); wc7 = MF16(a1, fW2K[15][lane], wc7);
            #pragma unroll
            for (int r = 0; r < 4; ++r){
                stag[g][quad*4+r][  0+col] = (_Float16)wc0[r];
                stag[g][quad*4+r][ 16+col] = (_Float16)wc1[r];
                stag[g][quad*4+r][ 32+col] = (_Float16)wc2[r];
                stag[g][quad*4+r][ 48+col] = (_Float16)wc3[r];
                stag[g][quad*4+r][ 64+col] = (_Float16)wc4[r];
                stag[g][quad*4+r][ 80+col] = (_Float16)wc5[r];
                stag[g][quad*4+r][ 96+col] = (_Float16)wc6[r];
                stag[g][quad*4+r][112+col] = (_Float16)wc7[r];
            }
            half8 w0h = *(const half8*)&stag[g][col][     quad*8];
            half8 w1h = *(const half8*)&stag[g][col][32 + quad*8];
            half8 w2h = *(const half8*)&stag[g][col][64 + quad*8];
            half8 w3h = *(const half8*)&stag[g][col][96 + quad*8];

            half8 fk0s0, fk0s1, fc0s0, fc0s1, fc1s0, fc1s1, fc2s0, fc2s1;
            #pragma unroll
            for (int j = 0; j < 8; ++j){
                float ww0=(float)w0h[j], ww1=(float)w1h[j];
                float ww2=(float)w2h[j], ww3=(float)w3h[j];
                float x0 = xs0[j];
                float xa = x1s[3*j], xb = x1s[3*j+1], xc = x1s[3*j+2];
                fk0s0[j] = (_Float16)(ww0 * x0 * y0);
                fk0s1[j] = (_Float16)(ww3 * (xa*y1a + xb*y1b + xc*y1c) * INV_SQRT3);
                fc0s0[j] = (_Float16)(ww1 * x0 * y1a);
                fc1s0[j] = (_Float16)(ww1 * x0 * y1b);
                fc2s0[j] = (_Float16)(ww1 * x0 * y1c);
                fc0s1[j] = (_Float16)(ww2 * xa * y0);
                fc1s1[j] = (_Float16)(ww2 * xb * y0);
                fc2s1[j] = (_Float16)(ww2 * xc * y0);
            }
            floatx4 k0a = MF16(fk0s0, fL0K[0][lane], zzero); k0a = MF16(fk0s1, fL0K[1][lane], k0a);
            floatx4 k0b = MF16(fk0s0, fL0K[2][lane], zzero); k0b = MF16(fk0s1, fL0K[3][lane], k0b);
            floatx4 kc0a = MF16(fc0s0, fL1K[0][lane], zzero); kc0a = MF16(fc0s1, fL1K[1][lane], kc0a);
            floatx4 kc0b = MF16(fc0s0, fL1K[2][lane], zzero); kc0b = MF16(fc0s1, fL1K[3][lane], kc0b);
            floatx4 kc1a = MF16(fc1s0, fL1K[0][lane], zzero); kc1a = MF16(fc1s1, fL1K[1][lane], kc1a);
            floatx4 kc1b = MF16(fc1s0, fL1K[2][lane], zzero); kc1b = MF16(fc1s1, fL1K[3][lane], kc1b);
            floatx4 kc2a = MF16(fc2s0, fL1K[0][lane], zzero); kc2a = MF16(fc2s1, fL1K[1][lane], kc2a);
            floatx4 kc2b = MF16(fc2s0, fL1K[2][lane], zzero); kc2b = MF16(fc2s1, fL1K[3][lane], kc2b);

            // d-stage: dd per edge row; 16-lane reduce; mask tail -> ev=0
            #pragma unroll
            for (int r = 0; r < 4; ++r){
                float dd = k0a[r]*qa.x + k0b[r]*qa.y + kc0a[r]*qa.z + kc1a[r]*qa.w
                         + kc2a[r]*qb.x + kc0b[r]*qb.y + kc1b[r]*qb.z + kc2b[r]*qb.w;
                dd += __shfl_xor(dd, 1);
                dd += __shfl_xor(dd, 2);
                dd += __shfl_xor(dd, 4);
                dd += __shfl_xor(dd, 8);
                // cutoff const: diff = pos[src]-pos[src] == 0 (reference bug)
                bool valid = (tb + quad*4 + r) < dcount;
                float ev = valid ? (0.9048374180359595f * expf(dd)) : 0.f;
                zacc += ev;
                float cf = sqrtf(ev);
                if (r==0) coef0 = cf; else if (r==1) coef1 = cf;
                else if (r==2) coef2 = cf; else coef3 = cf;
            }
        }

        // ================= V-PATH (reuses ea, xs, y) =================
        {
            floatx4 hA = MF16(ea, fW1V[0][lane], zzero);
            floatx4 hB = MF16(ea, fW1V[1][lane], zzero);
            floatx4 hC = MF16(ea, fW1V[2][lane], zzero);
            floatx4 hD = MF16(ea, fW1V[3][lane], zzero);
            #pragma unroll
            for (int r = 0; r < 4; ++r){
                stag[g][quad*4+r][   col] = (_Float16)sspf(hA[r]);
                stag[g][quad*4+r][16+col] = (_Float16)sspf(hB[r]);
                stag[g][quad*4+r][32+col] = (_Float16)sspf(hC[r]);
                stag[g][quad*4+r][48+col] = (_Float16)sspf(hD[r]);
            }
            half8 a0 = *(const half8*)&stag[g][col][quad*8];
            half8 a1 = *(const half8*)&stag[g][col][32 + quad*8];
            floatx4 wc0 = MF16(a0, fW2V[ 0][lane], zzero); wc0 = MF16(a1, fW2V[ 1][lane], wc0);
            floatx4 wc1 = MF16(a0, fW2V[ 2][lane], zzero); wc1 = MF16(a1, fW2V[ 3][lane], wc1);
            floatx4 wc2 = MF16(a0, fW2V[ 4][lane], zzero); wc2 = MF16(a1, fW2V[ 5][lane], wc2);
            floatx4 wc3 = MF16(a0, fW2V[ 6][lane], zzero); wc3 = MF16(a1, fW2V[ 7][lane], wc3);
            floatx4 wc4 = MF16(a0, fW2V[ 8][lane], zzero); wc4 = MF16(a1, fW2V[ 9][lane], wc4);
            floatx4 wc5 = MF16(a0, fW2V[10][lane], zzero); wc5 = MF16(a1, fW2V[11][lane], wc5);
            floatx4 wc6 = MF16(a0, fW2V[12][lane], zzero); wc6 = MF16(a1, fW2V[13][lane], wc6);
            floatx4 wc7 = MF16(a0, fW2V[14][lane], zzero); wc7 = MF16(a1, fW2V[15][lane], wc7);
            #pragma unroll
            for (int r = 0; r < 4; ++r){
                stag[g][quad*4+r][  0+col] = (_Float16)wc0[r];
                stag[g][quad*4+r][ 16+col] = (_Float16)wc1[r];
                stag[g][quad*4+r][ 32+col] = (_Float16)wc2[r];
                stag[g][quad*4+r][ 48+col] = (_Float16)wc3[r];
                stag[g][quad*4+r][ 64+col] = (_Float16)wc4[r];
                stag[g][quad*4+r][ 80+col] = (_Float16)wc5[r];
                stag[g][quad*4+r][ 96+col] = (_Float16)wc6[r];
                stag[g][quad*4+r][112+col] = (_Float16)wc7[r];
            }
            half8 w0h = *(const half8*)&stag[g][col][     quad*8];
            half8 w1h = *(const half8*)&stag[g][col][32 + quad*8];
            half8 w2h = *(const half8*)&stag[g][col][64 + quad*8];
            half8 w3h = *(const half8*)&stag[g][col][96 + quad*8];

            half8 fk0s0, fk0s1, fc0s0, fc0s1, fc1s0, fc1s1, fc2s0, fc2s1;
            #pragma unroll
            for (int j = 0; j < 8; ++j){
                float ww0=(float)w0h[j], ww1=(float)w1h[j];
                float ww2=(float)w2h[j], ww3=(float)w3h[j];
                float x0 = xs0[j];
                float xa = x1s[3*j], xb = x1s[3*j+1], xc = x1s[3*j+2];
                fk0s0[j] = (_Float16)(ww0 * x0 * y0);
                fk0s1[j] = (_Float16)(ww3 * (xa*y1a + xb*y1b + xc*y1c) * INV_SQRT3);
                fc0s0[j] = (_Float16)(ww1 * x0 * y1a);
                fc1s0[j] = (_Float16)(ww1 * x0 * y1b);
                fc2s0[j] = (_Float16)(ww1 * x0 * y1c);
                fc0s1[j] = (_Float16)(ww2 * xa * y0);
                fc1s1[j] = (_Float16)(ww2 * xb * y0);
                fc2s1[j] = (_Float16)(ww2 * xc * y0);
            }
            floatx4 k0a = MF16(fk0s0, fL0V[0][lane], zzero); k0a = MF16(fk0s1, fL0V[1][lane], k0a);
            floatx4 k0b = MF16(fk0s0, fL0V[2][lane], zzero); k0b = MF16(fk0s1, fL0V[3][lane], k0b);
            floatx4 kc0a = MF16(fc0s0, fL1V[0][lane], zzero); kc0a = MF16(fc0s1, fL1V[1][lane], kc0a);
            floatx4 kc0b = MF16(fc0s0, fL1V[2][lane], zzero); kc0b = MF16(fc0s1, fL1V[3][lane], kc0b);
            floatx4 kc1a = MF16(fc1s0, fL1V[0][lane], zzero); kc1a = MF16(fc1s1, fL1V[1][lane], kc1a);
            floatx4 kc1b = MF16(fc1s0, fL1V[2][lane], zzero); kc1b = MF16(fc1s1, fL1V[3][lane], kc1b);
            floatx4 kc2a = MF16(fc2s0, fL1V[0][lane], zzero); kc2a = MF16(fc2s1, fL1V[1][lane], kc2a);
            floatx4 kc2b = MF16(fc2s0, fL1V[2][lane], zzero); kc2b = MF16(fc2s1, fL1V[3][lane], kc2b);

            // register accumulation: macc += sqrt(ev_r) * v[r]
            macc0 += coef0*k0a[0] + coef1*k0a[1] + coef2*k0a[2] + coef3*k0a[3];
            macc1 += coef0*k0b[0] + coef1*k0b[1] + coef2*k0b[2] + coef3*k0b[3];
            macc2 += coef0*kc0a[0] + coef1*kc0a[1] + coef2*kc0a[2] + coef3*kc0a[3];
            macc3 += coef0*kc1a[0] + coef1*kc1a[1] + coef2*kc1a[2] + coef3*kc1a[3];
            macc4 += coef0*kc2a[0] + coef1*kc2a[1] + coef2*kc2a[2] + coef3*kc2a[3];
            macc5 += coef0*kc0b[0] + coef1*kc0b[1] + coef2*kc0b[2] + coef3*kc0b[3];
            macc6 += coef0*kc1b[0] + coef1*kc1b[1] + coef2*kc1b[2] + coef3*kc1b[3];
            macc7 += coef0*kc2b[0] + coef1*kc2b[1] + coef2*kc2b[2] + coef3*kc2b[3];
        }
    }

    // cross-quad reduction (z and the 8 channel accumulators)
    float z = zacc;
    z += __shfl_xor(z, 16); z += __shfl_xor(z, 32);
    macc0 += __shfl_xor(macc0, 16); macc0 += __shfl_xor(macc0, 32);
    macc1 += __shfl_xor(macc1, 16); macc1 += __shfl_xor(macc1, 32);
    macc2 += __shfl_xor(macc2, 16); macc2 += __shfl_xor(macc2, 32);
    macc3 += __shfl_xor(macc3, 16); macc3 += __shfl_xor(macc3, 32);
    macc4 += __shfl_xor(macc4, 16); macc4 += __shfl_xor(macc4, 32);
    macc5 += __shfl_xor(macc5, 16); macc5 += __shfl_xor(macc5, 32);
    macc6 += __shfl_xor(macc6, 16); macc6 += __shfl_xor(macc6, 32);
    macc7 += __shfl_xor(macc7, 16); macc7 += __shfl_xor(macc7, 32);

    float rz = (z > 0.f) ? rsqrtf(z) : 0.f;
    if (lane < 16){
        float* op = out + (size_t)n*128;
        op[col]                 += macc0 * rz;
        op[col + 16]            += macc1 * rz;
        op[32 + 3*col + 0]      += macc2 * rz;
        op[32 + 3*col + 1]      += macc3 * rz;
        op[32 + 3*col + 2]      += macc4 * rz;
        op[32 + 3*(col+16) + 0] += macc5 * rz;
        op[32 + 3*(col+16) + 1] += macc6 * rz;
        op[32 + 3*(col+16) + 2] += macc7 * rz;
    }
}

extern "C" void kernel_launch(void* const* d_in, const int* in_sizes, int n_in,
                              void* d_out, int out_size, void* d_ws, size_t ws_size,
                              hipStream_t stream)
{
    const float* feats = (const float*)d_in[0];
    const float* attrs = (const float*)d_in[1];
    const float* emb   = (const float*)d_in[2];
    const float* eattr = (const float*)d_in[3];
    // d_in[4] positions: unused (reference computes positions[src]-positions[src] == 0)
    const float* Wq0  = (const float*)d_in[5];
    const float* Wq1  = (const float*)d_in[6];
    const float* Wk1  = (const float*)d_in[7];
    const float* Wk2  = (const float*)d_in[8];
    const float* Wv1  = (const float*)d_in[9];
    const float* Wv2  = (const float*)d_in[10];
    const float* Wlk0 = (const float*)d_in[11];
    const float* Wlk1 = (const float*)d_in[12];
    const float* Wlv0 = (const float*)d_in[13];
    const float* Wlv1 = (const float*)d_in[14];
    const float* Wd0  = (const float*)d_in[15];
    const float* Wd1  = (const float*)d_in[16];
    const float* Ws0  = (const float*)d_in[17];
    const float* Ws1  = (const float*)d_in[18];
    const int*   eidx = (const int*)d_in[19];

    float* out   = (float*)d_out;
    float* qdbuf = (float*)d_ws;                       // N*128 (permuted qd)
    int*   degb  = (int*)(qdbuf + (size_t)N_NODES*128);// N
    int*   rowst = degb + N_NODES;                     // N+1
    int*   curs  = rowst + N_NODES + 1;                // N
    int*   perm  = curs + N_NODES;                     // E

    hipMemsetAsync(degb, 0, N_NODES*sizeof(int), stream);
    node_kernel<<<N_NODES, 128, 0, stream>>>(feats, attrs, Wq0, Wq1, Wd0, Wd1,
                                             Ws0, Ws1, qdbuf, out);
    count_kernel<<<N_EDGES/256, 256, 0, stream>>>(eidx, degb);
    scan_kernel<<<1, 256, 0, stream>>>(degb, rowst, curs);
    scatter_kernel<<<N_EDGES/256, 256, 0, stream>>>(eidx, curs, perm);
    edge_mfma<<<N_NODES/4, 256, 0, stream>>>(feats, emb, eattr, eidx,
                                             Wk1, Wk2, Wlk0, Wlk1,
                                             Wv1, Wv2, Wlv0, Wlv1,
                                             qdbuf, rowst, perm, out);
}

// Round 10
// 427.078 us; speedup vs baseline: 6.8441x; 1.3748x over previous
//
#include <hip/hip_runtime.h>
#include <math.h>

#define N_NODES 8192
#define N_EDGES 262144
#define INV_SQRT3 0.5773502691896258f

typedef __attribute__((ext_vector_type(8))) _Float16 half8;
typedef __attribute__((ext_vector_type(4))) float floatx4;

#define MF16(a,b,c) __builtin_amdgcn_mfma_f32_16x16x32_f16(a,b,c,0,0,0)

__device__ __forceinline__ float sspf(float x){
    // softplus(x) - ln2 via hw v_exp/v_log (~6 instr vs libm log1pf ~40)
    return (x > 20.0f) ? (x - 0.69314718f)
                       : (__logf(1.0f + __expf(x)) - 0.69314718f);
}

// ---------------------------------------------------------------------------
// Kernel A: per-node: out = sc (self-connection);
// qd = Wd^T q, all d-stage scales folded, stored PERMUTED:
// qdbuf[n][col*8+slot], slot = {qd0[c], qd0[c+16], qd1[3c..3c+2],
// qd1[3(c+16)..+2]} -> 2 float4 loads per lane in the K edge pass.
// ---------------------------------------------------------------------------
__global__ __launch_bounds__(128) void node_kernel(
    const float* __restrict__ feats, const float* __restrict__ attrs,
    const float* __restrict__ Wq0, const float* __restrict__ Wq1,
    const float* __restrict__ Wd0, const float* __restrict__ Wd1,
    const float* __restrict__ Ws0, const float* __restrict__ Ws1,
    float* __restrict__ qdbuf, float* __restrict__ out)
{
    int n = blockIdx.x; int t = threadIdx.x;
    __shared__ float sf[128];
    __shared__ float sa[16];
    __shared__ float sq[128];
    __shared__ float qsh[128];
    sf[t] = feats[n*128 + t];
    if (t < 16) sa[t] = attrs[n*16 + t];
    __syncthreads();
    const float inv_sqrt32 = 0.17677669529663687f;   // 1/sqrt(32)
    const float sc_scale   = 0.04419417382415922f;   // 1/sqrt(32*16)
    const float d_scale    = 0.022097086912079608f;  // 1/sqrt(2*32*32)
    float qv, scv;
    if (t < 32){
        int v = t;
        float acc = 0.f;
        for (int u = 0; u < 32; ++u) acc += sf[u] * Wq0[u*32 + v];
        qv = acc * inv_sqrt32;
        acc = 0.f;
        for (int u = 0; u < 32; ++u){
            float su = sf[u];
            for (int a = 0; a < 16; ++a)
                acc += su * sa[a] * Ws0[(u*16 + a)*32 + v];
        }
        scv = acc * sc_scale;
    } else {
        int k = t - 32; int v = k/3; int c = k - v*3;
        float acc = 0.f;
        for (int u = 0; u < 32; ++u) acc += sf[32 + u*3 + c] * Wq1[u*32 + v];
        qv = acc * inv_sqrt32;
        acc = 0.f;
        for (int u = 0; u < 32; ++u){
            float su = sf[32 + u*3 + c];
            for (int a = 0; a < 16; ++a)
                acc += su * sa[a] * Ws1[(u*16 + a)*32 + v];
        }
        scv = acc * sc_scale;
    }
    sq[t] = qv;
    out[n*128 + t] = scv;
    __syncthreads();

    float qd;
    if (t < 32){
        int v = t;
        float acc = 0.f;
        for (int u = 0; u < 32; ++u) acc += sq[u] * Wd0[u*32 + v];
        qd = acc * d_scale;
    } else {
        int k = t - 32; int v = k/3; int c = k - v*3;
        float acc = 0.f;
        for (int u = 0; u < 32; ++u) acc += sq[32 + u*3 + c] * Wd1[u*32 + v];
        qd = acc * d_scale * INV_SQRT3;
    }
    qsh[t] = qd;
    __syncthreads();
    {
        int col = t >> 3, slot = t & 7;
        int src;
        if      (slot == 0) src = col;
        else if (slot == 1) src = col + 16;
        else if (slot <  5) src = 32 + 3*col + (slot-2);
        else                src = 32 + 3*(col+16) + (slot-5);
        qdbuf[n*128 + t] = qsh[src];
    }
}

// ---------------------------------------------------------------------------
// CSR build: histogram by dst -> exclusive scan -> scatter permutation.
// ---------------------------------------------------------------------------
__global__ __launch_bounds__(256) void count_kernel(
    const int* __restrict__ eidx, int* __restrict__ degb)
{
    int e = blockIdx.x*256 + threadIdx.x;
    atomicAdd(&degb[eidx[N_EDGES + e]], 1);
}

__global__ __launch_bounds__(256) void scan_kernel(
    const int* __restrict__ degb, int* __restrict__ rowstart,
    int* __restrict__ cursor)
{
    __shared__ int part[256];
    int t = threadIdx.x;
    int loc[32];
    int s = 0;
    #pragma unroll
    for (int i = 0; i < 32; ++i){ loc[i] = s; s += degb[t*32 + i]; }
    part[t] = s;
    __syncthreads();
    for (int d = 1; d < 256; d <<= 1){
        int v = (t >= d) ? part[t-d] : 0;
        __syncthreads();
        part[t] += v;
        __syncthreads();
    }
    int excl = part[t] - s;
    #pragma unroll
    for (int i = 0; i < 32; ++i){
        int v = excl + loc[i];
        rowstart[t*32 + i] = v;
        cursor[t*32 + i]   = v;
    }
    if (t == 255) rowstart[N_NODES] = excl + s;
}

__global__ __launch_bounds__(256) void scatter_kernel(
    const int* __restrict__ eidx, int* __restrict__ cursor,
    int* __restrict__ perm)
{
    int e = blockIdx.x*256 + threadIdx.x;
    int p = atomicAdd(&cursor[eidx[N_EDGES + e]], 1);
    perm[p] = e;
}

// ---------------------------------------------------------------------------
// Node-centric MFMA edge pass, SINGLE path per kernel (28 KB weights +
// 17 KB staging = 46080 B -> 3 blocks/CU = 12 waves, vs merged 74.75 KB @ 2).
// PASS=1 (K): per tile compute ev; z in registers; cf=sqrt(ev) stored at CSR
//   slot (plain store); z stored per node. NO atomics.
// PASS=2 (V): load cf per row; macc += cf*v in registers; out += macc*rsqrt(z)
//   with plain stores. NO atomics.
// mfma_f32_16x16x32_f16 layouts (measured, learn_hip m89/m120):
// A[m=lane&15][k=quad*8+j]; B[k=quad*8+j][n=lane&15]; C col=lane&15,
// row=quad*4+reg.
// ---------------------------------------------------------------------------
template<int PASS>
__global__ __launch_bounds__(256, 3) void edge_pass(
    const float* __restrict__ feats, const float* __restrict__ emb,
    const float* __restrict__ eattr, const int* __restrict__ eidx,
    const float* __restrict__ W1,  const float* __restrict__ W2,
    const float* __restrict__ WL0, const float* __restrict__ WL1,
    const float* __restrict__ qdbuf,
    const int* __restrict__ rowstart, const int* __restrict__ perm,
    float* __restrict__ cfbuf, float* __restrict__ zbuf,
    float* __restrict__ out)
{
    __shared__ half8 fW1[4][64];
    __shared__ half8 fW2[16][64];
    __shared__ half8 fL0[4][64];
    __shared__ half8 fL1[4][64];
    __shared__ _Float16 stag[4][16][136];

    const int t    = threadIdx.x;
    const int lane = t & 63;
    const int col  = lane & 15;
    const int quad = lane >> 4;
    const int g    = t >> 6;

    // ---- preload weight fragments (scales folded) ----
    {
        half8 f;
        #pragma unroll
        for (int j = 0; j < 8; ++j){
            int k = quad*8 + j;
            f[j] = (k < 16) ? (_Float16)(W1[k*64 + g*16 + col] * 0.25f) : (_Float16)0.f;
        }
        fW1[g][lane] = f;
    }
    #pragma unroll
    for (int ff = 0; ff < 4; ++ff){
        int fr = g*4 + ff, tile = fr >> 1, s = fr & 1;
        half8 f;
        #pragma unroll
        for (int j = 0; j < 8; ++j)
            f[j] = (_Float16)(W2[(s*32 + quad*8 + j)*128 + tile*16 + col] * 0.125f);
        fW2[fr][lane] = f;
    }
    {
        int tile = g >> 1, s = g & 1;
        half8 f0, f1;
        #pragma unroll
        for (int j = 0; j < 8; ++j){
            int k = (s*32 + quad*8 + j)*32 + tile*16 + col;
            f0[j] = (_Float16)(WL0[k] * 0.125f);
            f1[j] = (_Float16)(WL1[k] * 0.125f);
        }
        fL0[g][lane] = f0; fL1[g][lane] = f1;
    }
    __syncthreads();     // the only block-wide barrier

    const floatx4 zzero = {0.f, 0.f, 0.f, 0.f};

    const int n  = blockIdx.x*4 + g;
    const int r0 = rowstart[n];
    const int dcount = rowstart[n+1] - r0;

    // PASS1: hoisted per-node qd (permuted layout -> 2 float4 per lane)
    float4 qa, qb;
    if (PASS == 1){
        const float* qdp = qdbuf + (size_t)n*128 + col*8;
        qa = *(const float4*)qdp;
        qb = *(const float4*)(qdp + 4);
    }
    // PASS2: per-node normalizer
    float rz = 0.f;
    if (PASS == 2){
        float z = zbuf[n];
        rz = (z > 0.f) ? rsqrtf(z) : 0.f;
    }

    // per-lane accumulators (named scalars; never indexable)
    float macc0=0.f, macc1=0.f, macc2=0.f, macc3=0.f;
    float macc4=0.f, macc5=0.f, macc6=0.f, macc7=0.f;
    float zacc = 0.f;

    for (int tb = 0; tb < dcount; tb += 16){
        // edge for this lane's A-column (clamped; tail rows masked)
        int slot = tb + col;
        int eA = perm[r0 + ((slot < dcount) ? slot : (dcount-1))];

        // ---- A-fragment: emb rows (K=16 zero-padded to 32) ----
        half8 ea;
        if (quad < 2){
            const float4* ep = (const float4*)(emb + (size_t)eA*16 + quad*8);
            float4 u0 = ep[0], u1 = ep[1];
            ea[0]=(_Float16)u0.x; ea[1]=(_Float16)u0.y; ea[2]=(_Float16)u0.z; ea[3]=(_Float16)u0.w;
            ea[4]=(_Float16)u1.x; ea[5]=(_Float16)u1.y; ea[6]=(_Float16)u1.z; ea[7]=(_Float16)u1.w;
        } else {
            #pragma unroll
            for (int j = 0; j < 8; ++j) ea[j] = (_Float16)0.f;
        }

        const int srcm = eidx[eA];
        const float* fsrc = feats + (size_t)srcm*128;
        float4 yv = *(const float4*)(eattr + (size_t)eA*4);
        const float y0 = yv.x, y1a = yv.y, y1b = yv.z, y1c = yv.w;

        float xs0[8];
        {
            float4 u0 = *(const float4*)(fsrc + quad*8);
            float4 u1 = *(const float4*)(fsrc + quad*8 + 4);
            xs0[0]=u0.x; xs0[1]=u0.y; xs0[2]=u0.z; xs0[3]=u0.w;
            xs0[4]=u1.x; xs0[5]=u1.y; xs0[6]=u1.z; xs0[7]=u1.w;
        }
        float x1s[24];
        #pragma unroll
        for (int q = 0; q < 6; ++q){
            float4 u = *(const float4*)(fsrc + 32 + quad*24 + q*4);
            x1s[q*4+0]=u.x; x1s[q*4+1]=u.y; x1s[q*4+2]=u.z; x1s[q*4+3]=u.w;
        }

        // ---- GEMM1 -> ssp -> h staging ----
        floatx4 hA = MF16(ea, fW1[0][lane], zzero);
        floatx4 hB = MF16(ea, fW1[1][lane], zzero);
        floatx4 hC = MF16(ea, fW1[2][lane], zzero);
        floatx4 hD = MF16(ea, fW1[3][lane], zzero);
        #pragma unroll
        for (int r = 0; r < 4; ++r){
            stag[g][quad*4+r][   col] = (_Float16)sspf(hA[r]);
            stag[g][quad*4+r][16+col] = (_Float16)sspf(hB[r]);
            stag[g][quad*4+r][32+col] = (_Float16)sspf(hC[r]);
            stag[g][quad*4+r][48+col] = (_Float16)sspf(hD[r]);
        }
        half8 a0 = *(const half8*)&stag[g][col][quad*8];
        half8 a1 = *(const half8*)&stag[g][col][32 + quad*8];

        // ---- GEMM2: w = h @ W2 (writes overlay h; same-wave DS in-order) ----
        floatx4 wc0 = MF16(a0, fW2[ 0][lane], zzero); wc0 = MF16(a1, fW2[ 1][lane], wc0);
        floatx4 wc1 = MF16(a0, fW2[ 2][lane], zzero); wc1 = MF16(a1, fW2[ 3][lane], wc1);
        floatx4 wc2 = MF16(a0, fW2[ 4][lane], zzero); wc2 = MF16(a1, fW2[ 5][lane], wc2);
        floatx4 wc3 = MF16(a0, fW2[ 6][lane], zzero); wc3 = MF16(a1, fW2[ 7][lane], wc3);
        floatx4 wc4 = MF16(a0, fW2[ 8][lane], zzero); wc4 = MF16(a1, fW2[ 9][lane], wc4);
        floatx4 wc5 = MF16(a0, fW2[10][lane], zzero); wc5 = MF16(a1, fW2[11][lane], wc5);
        floatx4 wc6 = MF16(a0, fW2[12][lane], zzero); wc6 = MF16(a1, fW2[13][lane], wc6);
        floatx4 wc7 = MF16(a0, fW2[14][lane], zzero); wc7 = MF16(a1, fW2[15][lane], wc7);
        #pragma unroll
        for (int r = 0; r < 4; ++r){
            stag[g][quad*4+r][  0+col] = (_Float16)wc0[r];
            stag[g][quad*4+r][ 16+col] = (_Float16)wc1[r];
            stag[g][quad*4+r][ 32+col] = (_Float16)wc2[r];
            stag[g][quad*4+r][ 48+col] = (_Float16)wc3[r];
            stag[g][quad*4+r][ 64+col] = (_Float16)wc4[r];
            stag[g][quad*4+r][ 80+col] = (_Float16)wc5[r];
            stag[g][quad*4+r][ 96+col] = (_Float16)wc6[r];
            stag[g][quad*4+r][112+col] = (_Float16)wc7[r];
        }
        half8 w0h = *(const half8*)&stag[g][col][     quad*8];
        half8 w1h = *(const half8*)&stag[g][col][32 + quad*8];
        half8 w2h = *(const half8*)&stag[g][col][64 + quad*8];
        half8 w3h = *(const half8*)&stag[g][col][96 + quad*8];

        // ---- uvu: km directly in lin A-frag layout ----
        half8 fk0s0, fk0s1, fc0s0, fc0s1, fc1s0, fc1s1, fc2s0, fc2s1;
        #pragma unroll
        for (int j = 0; j < 8; ++j){
            float ww0=(float)w0h[j], ww1=(float)w1h[j];
            float ww2=(float)w2h[j], ww3=(float)w3h[j];
            float x0 = xs0[j];
            float xa = x1s[3*j], xb = x1s[3*j+1], xc = x1s[3*j+2];
            fk0s0[j] = (_Float16)(ww0 * x0 * y0);
            fk0s1[j] = (_Float16)(ww3 * (xa*y1a + xb*y1b + xc*y1c) * INV_SQRT3);
            fc0s0[j] = (_Float16)(ww1 * x0 * y1a);
            fc1s0[j] = (_Float16)(ww1 * x0 * y1b);
            fc2s0[j] = (_Float16)(ww1 * x0 * y1c);
            fc0s1[j] = (_Float16)(ww2 * xa * y0);
            fc1s1[j] = (_Float16)(ww2 * xb * y0);
            fc2s1[j] = (_Float16)(ww2 * xc * y0);
        }

        // ---- lin: k/v = km @ WL ----
        floatx4 k0a = MF16(fk0s0, fL0[0][lane], zzero); k0a = MF16(fk0s1, fL0[1][lane], k0a);
        floatx4 k0b = MF16(fk0s0, fL0[2][lane], zzero); k0b = MF16(fk0s1, fL0[3][lane], k0b);
        floatx4 kc0a = MF16(fc0s0, fL1[0][lane], zzero); kc0a = MF16(fc0s1, fL1[1][lane], kc0a);
        floatx4 kc0b = MF16(fc0s0, fL1[2][lane], zzero); kc0b = MF16(fc0s1, fL1[3][lane], kc0b);
        floatx4 kc1a = MF16(fc1s0, fL1[0][lane], zzero); kc1a = MF16(fc1s1, fL1[1][lane], kc1a);
        floatx4 kc1b = MF16(fc1s0, fL1[2][lane], zzero); kc1b = MF16(fc1s1, fL1[3][lane], kc1b);
        floatx4 kc2a = MF16(fc2s0, fL1[0][lane], zzero); kc2a = MF16(fc2s1, fL1[1][lane], kc2a);
        floatx4 kc2b = MF16(fc2s0, fL1[2][lane], zzero); kc2b = MF16(fc2s1, fL1[3][lane], kc2b);

        if (PASS == 1){
            // d-stage: dd per row; 16-lane reduce; cf stored at CSR slot
            #pragma unroll
            for (int r = 0; r < 4; ++r){
                float dd = k0a[r]*qa.x + k0b[r]*qa.y + kc0a[r]*qa.z + kc1a[r]*qa.w
                         + kc2a[r]*qb.x + kc0b[r]*qb.y + kc1b[r]*qb.z + kc2b[r]*qb.w;
                dd += __shfl_xor(dd, 1);
                dd += __shfl_xor(dd, 2);
                dd += __shfl_xor(dd, 4);
                dd += __shfl_xor(dd, 8);
                // cutoff const: diff = pos[src]-pos[src] == 0 (reference bug)
                bool valid = (tb + quad*4 + r) < dcount;
                float ev = valid ? (0.9048374180359595f * __expf(dd)) : 0.f;
                zacc += ev;
                if (col == 0 && valid)
                    cfbuf[r0 + tb + quad*4 + r] = sqrtf(ev);
            }
        } else {
            // load cf per owned row (broadcast within quad via L1)
            float coef0, coef1, coef2, coef3;
            #pragma unroll
            for (int r = 0; r < 4; ++r){
                int sl = tb + quad*4 + r;
                float cf = (sl < dcount) ? cfbuf[r0 + sl] : 0.f;
                if (r==0) coef0 = cf; else if (r==1) coef1 = cf;
                else if (r==2) coef2 = cf; else coef3 = cf;
            }
            macc0 += coef0*k0a[0] + coef1*k0a[1] + coef2*k0a[2] + coef3*k0a[3];
            macc1 += coef0*k0b[0] + coef1*k0b[1] + coef2*k0b[2] + coef3*k0b[3];
            macc2 += coef0*kc0a[0] + coef1*kc0a[1] + coef2*kc0a[2] + coef3*kc0a[3];
            macc3 += coef0*kc1a[0] + coef1*kc1a[1] + coef2*kc1a[2] + coef3*kc1a[3];
            macc4 += coef0*kc2a[0] + coef1*kc2a[1] + coef2*kc2a[2] + coef3*kc2a[3];
            macc5 += coef0*kc0b[0] + coef1*kc0b[1] + coef2*kc0b[2] + coef3*kc0b[3];
            macc6 += coef0*kc1b[0] + coef1*kc1b[1] + coef2*kc1b[2] + coef3*kc1b[3];
            macc7 += coef0*kc2b[0] + coef1*kc2b[1] + coef2*kc2b[2] + coef3*kc2b[3];
        }
    }

    if (PASS == 1){
        float z = zacc;
        z += __shfl_xor(z, 16); z += __shfl_xor(z, 32);
        if (lane == 0) zbuf[n] = z;
    } else {
        macc0 += __shfl_xor(macc0, 16); macc0 += __shfl_xor(macc0, 32);
        macc1 += __shfl_xor(macc1, 16); macc1 += __shfl_xor(macc1, 32);
        macc2 += __shfl_xor(macc2, 16); macc2 += __shfl_xor(macc2, 32);
        macc3 += __shfl_xor(macc3, 16); macc3 += __shfl_xor(macc3, 32);
        macc4 += __shfl_xor(macc4, 16); macc4 += __shfl_xor(macc4, 32);
        macc5 += __shfl_xor(macc5, 16); macc5 += __shfl_xor(macc5, 32);
        macc6 += __shfl_xor(macc6, 16); macc6 += __shfl_xor(macc6, 32);
        macc7 += __shfl_xor(macc7, 16); macc7 += __shfl_xor(macc7, 32);
        if (lane < 16){
            float* op = out + (size_t)n*128;
            op[col]                 += macc0 * rz;
            op[col + 16]            += macc1 * rz;
            op[32 + 3*col + 0]      += macc2 * rz;
            op[32 + 3*col + 1]      += macc3 * rz;
            op[32 + 3*col + 2]      += macc4 * rz;
            op[32 + 3*(col+16) + 0] += macc5 * rz;
            op[32 + 3*(col+16) + 1] += macc6 * rz;
            op[32 + 3*(col+16) + 2] += macc7 * rz;
        }
    }
}

extern "C" void kernel_launch(void* const* d_in, const int* in_sizes, int n_in,
                              void* d_out, int out_size, void* d_ws, size_t ws_size,
                              hipStream_t stream)
{
    const float* feats = (const float*)d_in[0];
    const float* attrs = (const float*)d_in[1];
    const float* emb   = (const float*)d_in[2];
    const float* eattr = (const float*)d_in[3];
    // d_in[4] positions: unused (reference computes positions[src]-positions[src] == 0)
    const float* Wq0  = (const float*)d_in[5];
    const float* Wq1  = (const float*)d_in[6];
    const float* Wk1  = (const float*)d_in[7];
    const float* Wk2  = (const float*)d_in[8];
    const float* Wv1  = (const float*)d_in[9];
    const float* Wv2  = (const float*)d_in[10];
    const float* Wlk0 = (const float*)d_in[11];
    const float* Wlk1 = (const float*)d_in[12];
    const float* Wlv0 = (const float*)d_in[13];
    const float* Wlv1 = (const float*)d_in[14];
    const float* Wd0  = (const float*)d_in[15];
    const float* Wd1  = (const float*)d_in[16];
    const float* Ws0  = (const float*)d_in[17];
    const float* Ws1  = (const float*)d_in[18];
    const int*   eidx = (const int*)d_in[19];

    float* out   = (float*)d_out;
    float* qdbuf = (float*)d_ws;                        // N*128 (permuted qd)
    int*   degb  = (int*)(qdbuf + (size_t)N_NODES*128); // N
    int*   rowst = degb + N_NODES;                      // N+1
    int*   curs  = rowst + N_NODES + 1;                 // N
    int*   perm  = curs + N_NODES;                      // E
    float* cfbuf = (float*)(perm + N_EDGES);            // E
    float* zbuf  = cfbuf + N_EDGES;                     // N

    hipMemsetAsync(degb, 0, N_NODES*sizeof(int), stream);
    node_kernel<<<N_NODES, 128, 0, stream>>>(feats, attrs, Wq0, Wq1, Wd0, Wd1,
                                             Ws0, Ws1, qdbuf, out);
    count_kernel<<<N_EDGES/256, 256, 0, stream>>>(eidx, degb);
    scan_kernel<<<1, 256, 0, stream>>>(degb, rowst, curs);
    scatter_kernel<<<N_EDGES/256, 256, 0, stream>>>(eidx, curs, perm);
    edge_pass<1><<<N_NODES/4, 256, 0, stream>>>(feats, emb, eattr, eidx,
                                                Wk1, Wk2, Wlk0, Wlk1,
                                                qdbuf, rowst, perm,
                                                cfbuf, zbuf, out);
    edge_pass<2><<<N_NODES/4, 256, 0, stream>>>(feats, emb, eattr, eidx,
                                                Wv1, Wv2, Wlv0, Wlv1,
                                                qdbuf, rowst, perm,
                                                cfbuf, zbuf, out);
}

// Round 11
// 338.700 us; speedup vs baseline: 8.6300x; 1.2609x over previous
//
#include <hip/hip_runtime.h>
#include <math.h>

#define N_NODES 8192
#define N_EDGES 262144
#define INV_SQRT3 0.5773502691896258f

typedef __attribute__((ext_vector_type(8))) _Float16 half8;
typedef __attribute__((ext_vector_type(4))) float floatx4;

#define MF16(a,b,c) __builtin_amdgcn_mfma_f32_16x16x32_f16(a,b,c,0,0,0)

__device__ __forceinline__ float sspf(float x){
    // softplus(x) - ln2 via hw v_exp/v_log (~6 instr vs libm log1pf ~40)
    return (x > 20.0f) ? (x - 0.69314718f)
                       : (__logf(1.0f + __expf(x)) - 0.69314718f);
}

// ---------------------------------------------------------------------------
// Node kernel (factored): sc = einsum('nu,nuv->nv', s, T),
// T[n,u,v] = einsum('na,uav->nuv', attrs, Ws)  -- K=16 stage 1, T reused
// across the 3 c-planes of sc1 (402M -> 160M MACs). 4 nodes/block,
// 256 threads; T in LDS (stride-36 rows: bank-spread + 16B-aligned).
// Also computes q, qd (= Wd^T q, scales folded) and stores qd PERMUTED:
// qdbuf[n][col*8+slot], slot = {qd0[c], qd0[c+16], qd1[3c..+2], qd1[3(c+16)..+2]}.
// ---------------------------------------------------------------------------
__global__ __launch_bounds__(256) void node_kernel(
    const float* __restrict__ feats, const float* __restrict__ attrs,
    const float* __restrict__ Wq0, const float* __restrict__ Wq1,
    const float* __restrict__ Wd0, const float* __restrict__ Wd1,
    const float* __restrict__ Ws0, const float* __restrict__ Ws1,
    float* __restrict__ qdbuf, float* __restrict__ out)
{
    __shared__ float sa[4][16];
    __shared__ float sT[4][4][32];     // transposed activation planes
    __shared__ float Tl[2][4][1152];   // T, rows stride 36 (32 u + pad)
    __shared__ float qT[4][4][32];     // q, transposed planes
    __shared__ float qsh[4][128];      // qd standard layout

    const int t  = threadIdx.x;
    const int nb = blockIdx.x * 4;

    const float inv_sqrt32 = 0.17677669529663687f;   // 1/sqrt(32)
    const float sc_scale   = 0.04419417382415922f;   // 1/sqrt(32*16)
    const float d_scale    = 0.022097086912079608f;  // 1/sqrt(2*32*32)

    // ---- stage activations: sT[nn][p][u]; sa[nn][a] ----
    for (int i = t; i < 512; i += 256){
        int nn = i >> 7, r = i & 127;
        int p = r >> 5, u = r & 31;
        sT[nn][p][u] = feats[(size_t)(nb+nn)*128 + ((p==0) ? u : 32 + u*3 + (p-1))];
    }
    if (t < 64) sa[t>>4][t&15] = attrs[(size_t)(nb + (t>>4))*16 + (t&15)];
    __syncthreads();

    const int v  = t & 31;
    const int g5 = (t >> 5) & 3;
    const int hi = t >> 7;

    // ---- stage 1: Tl[m][nn][v*36+u] = sum_a sa[nn][a]*Ws_m[(u*16+a)*32+v] ----
    {
        const float* __restrict__ Wm = hi ? Ws1 : Ws0;
        float sar[4][16];
        #pragma unroll
        for (int nn = 0; nn < 4; ++nn)
            #pragma unroll
            for (int a = 0; a < 16; ++a) sar[nn][a] = sa[nn][a];
        #pragma unroll
        for (int uu = 0; uu < 8; ++uu){
            int u = g5*8 + uu;
            float a0=0.f, a1=0.f, a2=0.f, a3=0.f;
            #pragma unroll
            for (int a = 0; a < 16; ++a){
                float w = Wm[(u*16 + a)*32 + v];
                a0 += sar[0][a]*w; a1 += sar[1][a]*w;
                a2 += sar[2][a]*w; a3 += sar[3][a]*w;
            }
            Tl[hi][0][v*36+u] = a0; Tl[hi][1][v*36+u] = a1;
            Tl[hi][2][v*36+u] = a2; Tl[hi][3][v*36+u] = a3;
        }
    }
    __syncthreads();

    // ---- stage 2: thread = (team=hi, plane=g5, v); 2 nodes per thread ----
    const int p  = g5;
    const int n0 = hi*2, n1 = n0 + 1;
    const int mm = (p==0) ? 0 : 1;
    const float* __restrict__ Wqp = (p==0) ? Wq0 : Wq1;
    const float* __restrict__ Wdp = (p==0) ? Wd0 : Wd1;
    const int oidx = (p==0) ? v : 32 + v*3 + (p-1);

    // sc via b128 dot products against LDS-resident T
    float c0=0.f, c1=0.f;
    #pragma unroll
    for (int uc = 0; uc < 8; ++uc){
        float4 t0 = *(const float4*)&Tl[mm][n0][v*36 + uc*4];
        float4 t1 = *(const float4*)&Tl[mm][n1][v*36 + uc*4];
        float4 s0 = *(const float4*)&sT[n0][p][uc*4];
        float4 s1 = *(const float4*)&sT[n1][p][uc*4];
        c0 += t0.x*s0.x + t0.y*s0.y + t0.z*s0.z + t0.w*s0.w;
        c1 += t1.x*s1.x + t1.y*s1.y + t1.z*s1.z + t1.w*s1.w;
    }
    out[(size_t)(nb+n0)*128 + oidx] = c0 * sc_scale;
    out[(size_t)(nb+n1)*128 + oidx] = c1 * sc_scale;

    // q = s @ Wq / sqrt(32)  (Wq is 4 KB, L1-hot; sT broadcast reads)
    float q0=0.f, q1=0.f;
    #pragma unroll
    for (int u = 0; u < 32; ++u){
        float w = Wqp[u*32 + v];
        q0 += sT[n0][p][u] * w;
        q1 += sT[n1][p][u] * w;
    }
    qT[n0][p][v] = q0 * inv_sqrt32;
    qT[n1][p][v] = q1 * inv_sqrt32;
    __syncthreads();

    // qd = Wd^T q, scales folded
    float d0=0.f, d1=0.f;
    #pragma unroll
    for (int u = 0; u < 32; ++u){
        float w = Wdp[u*32 + v];
        d0 += qT[n0][p][u] * w;
        d1 += qT[n1][p][u] * w;
    }
    float dsc = (p==0) ? d_scale : d_scale * INV_SQRT3;
    qsh[n0][oidx] = d0 * dsc;
    qsh[n1][oidx] = d1 * dsc;
    __syncthreads();

    // permuted qd store
    for (int i = t; i < 512; i += 256){
        int nn = i >> 7, tt = i & 127;
        int col = tt >> 3, slot = tt & 7;
        int src;
        if      (slot == 0) src = col;
        else if (slot == 1) src = col + 16;
        else if (slot <  5) src = 32 + 3*col + (slot-2);
        else                src = 32 + 3*(col+16) + (slot-5);
        qdbuf[(size_t)(nb+nn)*128 + tt] = qsh[nn][src];
    }
}

// ---------------------------------------------------------------------------
// CSR build: histogram by dst -> exclusive scan -> scatter permutation.
// ---------------------------------------------------------------------------
__global__ __launch_bounds__(256) void count_kernel(
    const int* __restrict__ eidx, int* __restrict__ degb)
{
    int e = blockIdx.x*256 + threadIdx.x;
    atomicAdd(&degb[eidx[N_EDGES + e]], 1);
}

__global__ __launch_bounds__(256) void scan_kernel(
    const int* __restrict__ degb, int* __restrict__ rowstart,
    int* __restrict__ cursor)
{
    __shared__ int part[256];
    int t = threadIdx.x;
    int loc[32];
    int s = 0;
    #pragma unroll
    for (int i = 0; i < 32; ++i){ loc[i] = s; s += degb[t*32 + i]; }
    part[t] = s;
    __syncthreads();
    for (int d = 1; d < 256; d <<= 1){
        int v = (t >= d) ? part[t-d] : 0;
        __syncthreads();
        part[t] += v;
        __syncthreads();
    }
    int excl = part[t] - s;
    #pragma unroll
    for (int i = 0; i < 32; ++i){
        int v = excl + loc[i];
        rowstart[t*32 + i] = v;
        cursor[t*32 + i]   = v;
    }
    if (t == 255) rowstart[N_NODES] = excl + s;
}

__global__ __launch_bounds__(256) void scatter_kernel(
    const int* __restrict__ eidx, int* __restrict__ cursor,
    int* __restrict__ perm)
{
    int e = blockIdx.x*256 + threadIdx.x;
    int p = atomicAdd(&cursor[eidx[N_EDGES + e]], 1);
    perm[p] = e;
}

// ---------------------------------------------------------------------------
// Node-centric MFMA edge pass, SINGLE path per kernel (28 KB weights +
// 17 KB staging = 46080 B -> 3 blocks/CU = 12 waves).
// PASS=1 (K): per tile compute ev; z in registers; cf=sqrt(ev) stored at CSR
//   slot (plain store); z stored per node. NO atomics.
// PASS=2 (V): load cf per row; macc += cf*v in registers; out += macc*rsqrt(z)
//   with plain stores. NO atomics.
// mfma_f32_16x16x32_f16 layouts (measured, learn_hip m89/m120):
// A[m=lane&15][k=quad*8+j]; B[k=quad*8+j][n=lane&15]; C col=lane&15,
// row=quad*4+reg.
// ---------------------------------------------------------------------------
template<int PASS>
__global__ __launch_bounds__(256, 3) void edge_pass(
    const float* __restrict__ feats, const float* __restrict__ emb,
    const float* __restrict__ eattr, const int* __restrict__ eidx,
    const float* __restrict__ W1,  const float* __restrict__ W2,
    const float* __restrict__ WL0, const float* __restrict__ WL1,
    const float* __restrict__ qdbuf,
    const int* __restrict__ rowstart, const int* __restrict__ perm,
    float* __restrict__ cfbuf, float* __restrict__ zbuf,
    float* __restrict__ out)
{
    __shared__ half8 fW1[4][64];
    __shared__ half8 fW2[16][64];
    __shared__ half8 fL0[4][64];
    __shared__ half8 fL1[4][64];
    __shared__ _Float16 stag[4][16][136];

    const int t    = threadIdx.x;
    const int lane = t & 63;
    const int col  = lane & 15;
    const int quad = lane >> 4;
    const int g    = t >> 6;

    // ---- preload weight fragments (scales folded) ----
    {
        half8 f;
        #pragma unroll
        for (int j = 0; j < 8; ++j){
            int k = quad*8 + j;
            f[j] = (k < 16) ? (_Float16)(W1[k*64 + g*16 + col] * 0.25f) : (_Float16)0.f;
        }
        fW1[g][lane] = f;
    }
    #pragma unroll
    for (int ff = 0; ff < 4; ++ff){
        int fr = g*4 + ff, tile = fr >> 1, s = fr & 1;
        half8 f;
        #pragma unroll
        for (int j = 0; j < 8; ++j)
            f[j] = (_Float16)(W2[(s*32 + quad*8 + j)*128 + tile*16 + col] * 0.125f);
        fW2[fr][lane] = f;
    }
    {
        int tile = g >> 1, s = g & 1;
        half8 f0, f1;
        #pragma unroll
        for (int j = 0; j < 8; ++j){
            int k = (s*32 + quad*8 + j)*32 + tile*16 + col;
            f0[j] = (_Float16)(WL0[k] * 0.125f);
            f1[j] = (_Float16)(WL1[k] * 0.125f);
        }
        fL0[g][lane] = f0; fL1[g][lane] = f1;
    }
    __syncthreads();     // the only block-wide barrier

    const floatx4 zzero = {0.f, 0.f, 0.f, 0.f};

    const int n  = blockIdx.x*4 + g;
    const int r0 = rowstart[n];
    const int dcount = rowstart[n+1] - r0;

    // PASS1: hoisted per-node qd (permuted layout -> 2 float4 per lane)
    float4 qa, qb;
    if (PASS == 1){
        const float* qdp = qdbuf + (size_t)n*128 + col*8;
        qa = *(const float4*)qdp;
        qb = *(const float4*)(qdp + 4);
    }
    // PASS2: per-node normalizer
    float rz = 0.f;
    if (PASS == 2){
        float z = zbuf[n];
        rz = (z > 0.f) ? rsqrtf(z) : 0.f;
    }

    // per-lane accumulators (named scalars; never indexable)
    float macc0=0.f, macc1=0.f, macc2=0.f, macc3=0.f;
    float macc4=0.f, macc5=0.f, macc6=0.f, macc7=0.f;
    float zacc = 0.f;

    for (int tb = 0; tb < dcount; tb += 16){
        // edge for this lane's A-column (clamped; tail rows masked)
        int slot = tb + col;
        int eA = perm[r0 + ((slot < dcount) ? slot : (dcount-1))];

        // ---- A-fragment: emb rows (K=16 zero-padded to 32) ----
        half8 ea;
        if (quad < 2){
            const float4* ep = (const float4*)(emb + (size_t)eA*16 + quad*8);
            float4 u0 = ep[0], u1 = ep[1];
            ea[0]=(_Float16)u0.x; ea[1]=(_Float16)u0.y; ea[2]=(_Float16)u0.z; ea[3]=(_Float16)u0.w;
            ea[4]=(_Float16)u1.x; ea[5]=(_Float16)u1.y; ea[6]=(_Float16)u1.z; ea[7]=(_Float16)u1.w;
        } else {
            #pragma unroll
            for (int j = 0; j < 8; ++j) ea[j] = (_Float16)0.f;
        }

        const int srcm = eidx[eA];
        const float* fsrc = feats + (size_t)srcm*128;
        float4 yv = *(const float4*)(eattr + (size_t)eA*4);
        const float y0 = yv.x, y1a = yv.y, y1b = yv.z, y1c = yv.w;

        float xs0[8];
        {
            float4 u0 = *(const float4*)(fsrc + quad*8);
            float4 u1 = *(const float4*)(fsrc + quad*8 + 4);
            xs0[0]=u0.x; xs0[1]=u0.y; xs0[2]=u0.z; xs0[3]=u0.w;
            xs0[4]=u1.x; xs0[5]=u1.y; xs0[6]=u1.z; xs0[7]=u1.w;
        }
        float x1s[24];
        #pragma unroll
        for (int q = 0; q < 6; ++q){
            float4 u = *(const float4*)(fsrc + 32 + quad*24 + q*4);
            x1s[q*4+0]=u.x; x1s[q*4+1]=u.y; x1s[q*4+2]=u.z; x1s[q*4+3]=u.w;
        }

        // ---- GEMM1 -> ssp -> h staging ----
        floatx4 hA = MF16(ea, fW1[0][lane], zzero);
        floatx4 hB = MF16(ea, fW1[1][lane], zzero);
        floatx4 hC = MF16(ea, fW1[2][lane], zzero);
        floatx4 hD = MF16(ea, fW1[3][lane], zzero);
        #pragma unroll
        for (int r = 0; r < 4; ++r){
            stag[g][quad*4+r][   col] = (_Float16)sspf(hA[r]);
            stag[g][quad*4+r][16+col] = (_Float16)sspf(hB[r]);
            stag[g][quad*4+r][32+col] = (_Float16)sspf(hC[r]);
            stag[g][quad*4+r][48+col] = (_Float16)sspf(hD[r]);
        }
        half8 a0 = *(const half8*)&stag[g][col][quad*8];
        half8 a1 = *(const half8*)&stag[g][col][32 + quad*8];

        // ---- GEMM2: w = h @ W2 (writes overlay h; same-wave DS in-order) ----
        floatx4 wc0 = MF16(a0, fW2[ 0][lane], zzero); wc0 = MF16(a1, fW2[ 1][lane], wc0);
        floatx4 wc1 = MF16(a0, fW2[ 2][lane], zzero); wc1 = MF16(a1, fW2[ 3][lane], wc1);
        floatx4 wc2 = MF16(a0, fW2[ 4][lane], zzero); wc2 = MF16(a1, fW2[ 5][lane], wc2);
        floatx4 wc3 = MF16(a0, fW2[ 6][lane], zzero); wc3 = MF16(a1, fW2[ 7][lane], wc3);
        floatx4 wc4 = MF16(a0, fW2[ 8][lane], zzero); wc4 = MF16(a1, fW2[ 9][lane], wc4);
        floatx4 wc5 = MF16(a0, fW2[10][lane], zzero); wc5 = MF16(a1, fW2[11][lane], wc5);
        floatx4 wc6 = MF16(a0, fW2[12][lane], zzero); wc6 = MF16(a1, fW2[13][lane], wc6);
        floatx4 wc7 = MF16(a0, fW2[14][lane], zzero); wc7 = MF16(a1, fW2[15][lane], wc7);
        #pragma unroll
        for (int r = 0; r < 4; ++r){
            stag[g][quad*4+r][  0+col] = (_Float16)wc0[r];
            stag[g][quad*4+r][ 16+col] = (_Float16)wc1[r];
            stag[g][quad*4+r][ 32+col] = (_Float16)wc2[r];
            stag[g][quad*4+r][ 48+col] = (_Float16)wc3[r];
            stag[g][quad*4+r][ 64+col] = (_Float16)wc4[r];
            stag[g][quad*4+r][ 80+col] = (_Float16)wc5[r];
            stag[g][quad*4+r][ 96+col] = (_Float16)wc6[r];
            stag[g][quad*4+r][112+col] = (_Float16)wc7[r];
        }
        half8 w0h = *(const half8*)&stag[g][col][     quad*8];
        half8 w1h = *(const half8*)&stag[g][col][32 + quad*8];
        half8 w2h = *(const half8*)&stag[g][col][64 + quad*8];
        half8 w3h = *(const half8*)&stag[g][col][96 + quad*8];

        // ---- uvu: km directly in lin A-frag layout ----
        half8 fk0s0, fk0s1, fc0s0, fc0s1, fc1s0, fc1s1, fc2s0, fc2s1;
        #pragma unroll
        for (int j = 0; j < 8; ++j){
            float ww0=(float)w0h[j], ww1=(float)w1h[j];
            float ww2=(float)w2h[j], ww3=(float)w3h[j];
            float x0 = xs0[j];
            float xa = x1s[3*j], xb = x1s[3*j+1], xc = x1s[3*j+2];
            fk0s0[j] = (_Float16)(ww0 * x0 * y0);
            fk0s1[j] = (_Float16)(ww3 * (xa*y1a + xb*y1b + xc*y1c) * INV_SQRT3);
            fc0s0[j] = (_Float16)(ww1 * x0 * y1a);
            fc1s0[j] = (_Float16)(ww1 * x0 * y1b);
            fc2s0[j] = (_Float16)(ww1 * x0 * y1c);
            fc0s1[j] = (_Float16)(ww2 * xa * y0);
            fc1s1[j] = (_Float16)(ww2 * xb * y0);
            fc2s1[j] = (_Float16)(ww2 * xc * y0);
        }

        // ---- lin: k/v = km @ WL ----
        floatx4 k0a = MF16(fk0s0, fL0[0][lane], zzero); k0a = MF16(fk0s1, fL0[1][lane], k0a);
        floatx4 k0b = MF16(fk0s0, fL0[2][lane], zzero); k0b = MF16(fk0s1, fL0[3][lane], k0b);
        floatx4 kc0a = MF16(fc0s0, fL1[0][lane], zzero); kc0a = MF16(fc0s1, fL1[1][lane], kc0a);
        floatx4 kc0b = MF16(fc0s0, fL1[2][lane], zzero); kc0b = MF16(fc0s1, fL1[3][lane], kc0b);
        floatx4 kc1a = MF16(fc1s0, fL1[0][lane], zzero); kc1a = MF16(fc1s1, fL1[1][lane], kc1a);
        floatx4 kc1b = MF16(fc1s0, fL1[2][lane], zzero); kc1b = MF16(fc1s1, fL1[3][lane], kc1b);
        floatx4 kc2a = MF16(fc2s0, fL1[0][lane], zzero); kc2a = MF16(fc2s1, fL1[1][lane], kc2a);
        floatx4 kc2b = MF16(fc2s0, fL1[2][lane], zzero); kc2b = MF16(fc2s1, fL1[3][lane], kc2b);

        if (PASS == 1){
            // d-stage: dd per row; 16-lane reduce; cf stored at CSR slot
            #pragma unroll
            for (int r = 0; r < 4; ++r){
                float dd = k0a[r]*qa.x + k0b[r]*qa.y + kc0a[r]*qa.z + kc1a[r]*qa.w
                         + kc2a[r]*qb.x + kc0b[r]*qb.y + kc1b[r]*qb.z + kc2b[r]*qb.w;
                dd += __shfl_xor(dd, 1);
                dd += __shfl_xor(dd, 2);
                dd += __shfl_xor(dd, 4);
                dd += __shfl_xor(dd, 8);
                // cutoff const: diff = pos[src]-pos[src] == 0 (reference bug)
                bool valid = (tb + quad*4 + r) < dcount;
                float ev = valid ? (0.9048374180359595f * __expf(dd)) : 0.f;
                zacc += ev;
                if (col == 0 && valid)
                    cfbuf[r0 + tb + quad*4 + r] = sqrtf(ev);
            }
        } else {
            // load cf per owned row (broadcast within quad via L1)
            float coef0, coef1, coef2, coef3;
            #pragma unroll
            for (int r = 0; r < 4; ++r){
                int sl = tb + quad*4 + r;
                float cf = (sl < dcount) ? cfbuf[r0 + sl] : 0.f;
                if (r==0) coef0 = cf; else if (r==1) coef1 = cf;
                else if (r==2) coef2 = cf; else coef3 = cf;
            }
            macc0 += coef0*k0a[0] + coef1*k0a[1] + coef2*k0a[2] + coef3*k0a[3];
            macc1 += coef0*k0b[0] + coef1*k0b[1] + coef2*k0b[2] + coef3*k0b[3];
            macc2 += coef0*kc0a[0] + coef1*kc0a[1] + coef2*kc0a[2] + coef3*kc0a[3];
            macc3 += coef0*kc1a[0] + coef1*kc1a[1] + coef2*kc1a[2] + coef3*kc1a[3];
            macc4 += coef0*kc2a[0] + coef1*kc2a[1] + coef2*kc2a[2] + coef3*kc2a[3];
            macc5 += coef0*kc0b[0] + coef1*kc0b[1] + coef2*kc0b[2] + coef3*kc0b[3];
            macc6 += coef0*kc1b[0] + coef1*kc1b[1] + coef2*kc1b[2] + coef3*kc1b[3];
            macc7 += coef0*kc2b[0] + coef1*kc2b[1] + coef2*kc2b[2] + coef3*kc2b[3];
        }
    }

    if (PASS == 1){
        float z = zacc;
        z += __shfl_xor(z, 16); z += __shfl_xor(z, 32);
        if (lane == 0) zbuf[n] = z;
    } else {
        macc0 += __shfl_xor(macc0, 16); macc0 += __shfl_xor(macc0, 32);
        macc1 += __shfl_xor(macc1, 16); macc1 += __shfl_xor(macc1, 32);
        macc2 += __shfl_xor(macc2, 16); macc2 += __shfl_xor(macc2, 32);
        macc3 += __shfl_xor(macc3, 16); macc3 += __shfl_xor(macc3, 32);
        macc4 += __shfl_xor(macc4, 16); macc4 += __shfl_xor(macc4, 32);
        macc5 += __shfl_xor(macc5, 16); macc5 += __shfl_xor(macc5, 32);
        macc6 += __shfl_xor(macc6, 16); macc6 += __shfl_xor(macc6, 32);
        macc7 += __shfl_xor(macc7, 16); macc7 += __shfl_xor(macc7, 32);
        if (lane < 16){
            float* op = out + (size_t)n*128;
            op[col]                 += macc0 * rz;
            op[col + 16]            += macc1 * rz;
            op[32 + 3*col + 0]      += macc2 * rz;
            op[32 + 3*col + 1]      += macc3 * rz;
            op[32 + 3*col + 2]      += macc4 * rz;
            op[32 + 3*(col+16) + 0] += macc5 * rz;
            op[32 + 3*(col+16) + 1] += macc6 * rz;
            op[32 + 3*(col+16) + 2] += macc7 * rz;
        }
    }
}

extern "C" void kernel_launch(void* const* d_in, const int* in_sizes, int n_in,
                              void* d_out, int out_size, void* d_ws, size_t ws_size,
                              hipStream_t stream)
{
    const float* feats = (const float*)d_in[0];
    const float* attrs = (const float*)d_in[1];
    const float* emb   = (const float*)d_in[2];
    const float* eattr = (const float*)d_in[3];
    // d_in[4] positions: unused (reference computes positions[src]-positions[src] == 0)
    const float* Wq0  = (const float*)d_in[5];
    const float* Wq1  = (const float*)d_in[6];
    const float* Wk1  = (const float*)d_in[7];
    const float* Wk2  = (const float*)d_in[8];
    const float* Wv1  = (const float*)d_in[9];
    const float* Wv2  = (const float*)d_in[10];
    const float* Wlk0 = (const float*)d_in[11];
    const float* Wlk1 = (const float*)d_in[12];
    const float* Wlv0 = (const float*)d_in[13];
    const float* Wlv1 = (const float*)d_in[14];
    const float* Wd0  = (const float*)d_in[15];
    const float* Wd1  = (const float*)d_in[16];
    const float* Ws0  = (const float*)d_in[17];
    const float* Ws1  = (const float*)d_in[18];
    const int*   eidx = (const int*)d_in[19];

    float* out   = (float*)d_out;
    float* qdbuf = (float*)d_ws;                        // N*128 (permuted qd)
    int*   degb  = (int*)(qdbuf + (size_t)N_NODES*128); // N
    int*   rowst = degb + N_NODES;                      // N+1
    int*   curs  = rowst + N_NODES + 1;                 // N
    int*   perm  = curs + N_NODES;                      // E
    float* cfbuf = (float*)(perm + N_EDGES);            // E
    float* zbuf  = cfbuf + N_EDGES;                     // N

    hipMemsetAsync(degb, 0, N_NODES*sizeof(int), stream);
    node_kernel<<<N_NODES/4, 256, 0, stream>>>(feats, attrs, Wq0, Wq1, Wd0, Wd1,
                                               Ws0, Ws1, qdbuf, out);
    count_kernel<<<N_EDGES/256, 256, 0, stream>>>(eidx, degb);
    scan_kernel<<<1, 256, 0, stream>>>(degb, rowst, curs);
    scatter_kernel<<<N_EDGES/256, 256, 0, stream>>>(eidx, curs, perm);
    edge_pass<1><<<N_NODES/4, 256, 0, stream>>>(feats, emb, eattr, eidx,
                                                Wk1, Wk2, Wlk0, Wlk1,
                                                qdbuf, rowst, perm,
                                                cfbuf, zbuf, out);
    edge_pass<2><<<N_NODES/4, 256, 0, stream>>>(feats, emb, eattr, eidx,
                                                Wv1, Wv2, Wlv0, Wlv1,
                                                qdbuf, rowst, perm,
                                                cfbuf, zbuf, out);
}